// Round 1
// baseline (1268.050 us; speedup 1.0000x reference)
//
#include <hip/hip_runtime.h>
#include <hip/hip_bf16.h>

#define BB 4
#define DEPTH 160
#define CC 96
#define NN 2560          // DEPTH*16
#define NHH 4
#define HD 24
#define THETA 0.6f
#define BN_EPS 1e-5f

// ---------------------------------------------------------------------------
// Workspace layout (floats):
//   wq_eff : 27*96*96 = 248832        [tap][ic][oc], BN scale folded, center tap TCDC-corrected
//   wk_eff : 248832
//   wv_t   : 9216                     [ic][oc]
//   bias_q : 96
//   bias_k : 96
//   Q,K,V,att : 4 * (B*N*C = 983040)
// total = 4,439,232 floats = 17.8 MB
// ---------------------------------------------------------------------------
#define WS_WQ   0
#define WS_WK   248832
#define WS_WV   497664
#define WS_BQ   506880
#define WS_BK   506976
#define WS_Q    507072
#define WS_K    1490112
#define WS_V    2473152
#define WS_ATT  3456192

// Fold TCDC center-tap correction + BN scale into conv weights; layout [tap][ic][oc].
__global__ void prep_w(const float* __restrict__ w, const float* __restrict__ gamma,
                       const float* __restrict__ beta, const float* __restrict__ mean,
                       const float* __restrict__ var, float* __restrict__ w_eff,
                       float* __restrict__ bias) {
    int oc = blockIdx.x;
    int ic = threadIdx.x;
    if (ic >= CC) return;
    float scale = gamma[oc] * rsqrtf(var[oc] + BN_EPS);
    if (ic == 0) bias[oc] = beta[oc] - mean[oc] * scale;
    const float* wp = w + (oc * CC + ic) * 27;
    float kdiff = 0.f;
#pragma unroll
    for (int t = 0; t < 9; ++t) kdiff += wp[t] + wp[18 + t];
#pragma unroll
    for (int t = 0; t < 27; ++t) {
        float v = wp[t];
        if (t == 13) v -= THETA * kdiff;     // center tap (1,1,1)
        w_eff[t * (CC * CC) + ic * CC + oc] = v * scale;
    }
}

__global__ void prep_v(const float* __restrict__ wv, float* __restrict__ wv_t) {
    int oc = blockIdx.x;
    int ic = threadIdx.x;
    if (ic < CC) wv_t[ic * CC + oc] = wv[oc * CC + ic];
}

// One block = (96 oc, 2 depths). LDS holds 4 depth slices of x (channel-last).
__global__ __launch_bounds__(192) void qkv_conv(
        const float* __restrict__ x, const float* __restrict__ wq_eff,
        const float* __restrict__ wk_eff, const float* __restrict__ wv_t,
        const float* __restrict__ bias_q, const float* __restrict__ bias_k,
        float* __restrict__ Q, float* __restrict__ K, float* __restrict__ V) {
    __shared__ float xs[4 * 16 * CC];   // [slice][spatial 0..15][ic]  24 KB
    const int b = blockIdx.y;
    const int d0 = blockIdx.x * 2;
    const int oc = threadIdx.x;         // 0..95
    const int y = threadIdx.y;          // 0..1
    const int tid = threadIdx.y * 96 + threadIdx.x;

    for (int i = tid; i < 4 * 16 * CC; i += 192) {
        int ic = i % CC;
        int r  = i / CC;
        int p  = r % 16;
        int s  = r / 16;
        int dg = d0 - 1 + s;
        float v = 0.f;
        if (dg >= 0 && dg < DEPTH)
            v = x[((size_t)b * NN + dg * 16 + p) * CC + ic];
        xs[i] = v;
    }
    __syncthreads();

    float aq[16], ak[16], av[16];
#pragma unroll
    for (int sp = 0; sp < 16; ++sp) { aq[sp] = 0.f; ak[sp] = 0.f; av[sp] = 0.f; }

    const int d = d0 + y;

#pragma unroll
    for (int kd = 0; kd < 3; ++kd) {
        const float* xsl = xs + (y + kd) * (16 * CC);
#pragma unroll
        for (int kh = 0; kh < 3; ++kh) {
#pragma unroll
            for (int kw = 0; kw < 3; ++kw) {
                const int tap = kd * 9 + kh * 3 + kw;
                const float* wq_p = wq_eff + tap * (CC * CC) + oc;
                const float* wk_p = wk_eff + tap * (CC * CC) + oc;
#pragma unroll 2
                for (int ic = 0; ic < CC; ++ic) {
                    float wq_v = wq_p[ic * CC];
                    float wk_v = wk_p[ic * CC];
#pragma unroll
                    for (int sp = 0; sp < 16; ++sp) {
                        const int hh = (sp >> 2) + kh - 1;
                        const int ww = (sp & 3) + kw - 1;
                        if (hh >= 0 && hh < 4 && ww >= 0 && ww < 4) {
                            float xv = xsl[(hh * 4 + ww) * CC + ic];
                            aq[sp] += wq_v * xv;
                            ak[sp] += wk_v * xv;
                        }
                    }
                }
            }
        }
    }
    // 1x1x1 V conv (center slice y+1)
    {
        const float* xsl = xs + (y + 1) * (16 * CC);
#pragma unroll 2
        for (int ic = 0; ic < CC; ++ic) {
            float wv_v = wv_t[ic * CC + oc];
#pragma unroll
            for (int sp = 0; sp < 16; ++sp)
                av[sp] += wv_v * xsl[sp * CC + ic];
        }
    }

    const float bq = bias_q[oc], bk = bias_k[oc];
#pragma unroll
    for (int sp = 0; sp < 16; ++sp) {
        size_t o = ((size_t)b * NN + d * 16 + sp) * CC + oc;
        Q[o] = aq[sp] + bq;
        K[o] = ak[sp] + bk;
        V[o] = av[sp];
    }
}

// Flash-style attention: one query row per thread, K/V tiles of 128 in LDS,
// lazy online softmax in exp2 domain (log2e/sqrt(HD) folded into q).
__global__ __launch_bounds__(128) void attn_kernel(
        const float* __restrict__ Q, const float* __restrict__ K,
        const float* __restrict__ V, const float* __restrict__ sgp,
        float* __restrict__ att) {
    __shared__ float kt[128][HD];
    __shared__ float vt[128][HD];
    const int b = blockIdx.z, h = blockIdx.y;
    const int qi = blockIdx.x * 128 + threadIdx.x;
    const float qscale = 1.4426950408889634f / sgp[0];

    float qr[HD];
    const float* qp = Q + ((size_t)b * NN + qi) * CC + h * HD;
#pragma unroll
    for (int j = 0; j < HD; ++j) qr[j] = qp[j] * qscale;

    float acc[HD];
#pragma unroll
    for (int j = 0; j < HD; ++j) acc[j] = 0.f;
    float mx = -3.0e38f, l = 0.f;

    const float* kb = K + (size_t)b * NN * CC + h * HD;
    const float* vb = V + (size_t)b * NN * CC + h * HD;

    for (int t0 = 0; t0 < NN; t0 += 128) {
        for (int i = threadIdx.x; i < 128 * HD; i += 128) {
            int m = i / HD, j = i % HD;
            kt[m][j] = kb[(size_t)(t0 + m) * CC + j];
            vt[m][j] = vb[(size_t)(t0 + m) * CC + j];
        }
        __syncthreads();

        for (int m = 0; m < 128; ++m) {
            float s0 = qr[0] * kt[m][0], s1 = qr[1] * kt[m][1];
            float s2 = qr[2] * kt[m][2], s3 = qr[3] * kt[m][3];
#pragma unroll
            for (int j = 4; j < HD; j += 4) {
                s0 += qr[j + 0] * kt[m][j + 0];
                s1 += qr[j + 1] * kt[m][j + 1];
                s2 += qr[j + 2] * kt[m][j + 2];
                s3 += qr[j + 3] * kt[m][j + 3];
            }
            float s = (s0 + s1) + (s2 + s3);
            if (s > mx) {                       // rare (~log N times)
                float corr = exp2f(mx - s);
                l *= corr;
#pragma unroll
                for (int j = 0; j < HD; ++j) acc[j] *= corr;
                mx = s;
            }
            float p = exp2f(s - mx);
            l += p;
#pragma unroll
            for (int j = 0; j < HD; ++j) acc[j] += p * vt[m][j];
        }
        __syncthreads();
    }

    float rl = 1.0f / l;
    float* op = att + ((size_t)b * NN + qi) * CC + h * HD;
#pragma unroll
    for (int j = 0; j < HD; ++j) op[j] = acc[j] * rl;
}

// out[t,c] = bo[c] + sum_cp att[t,cp] * wo[c,cp]
__global__ __launch_bounds__(256) void proj_kernel(
        const float* __restrict__ att, const float* __restrict__ wo,
        const float* __restrict__ bo, float* __restrict__ out) {
    __shared__ float wt[CC][CC + 1];   // wt[cp][c] = wo[c][cp], padded
    for (int i = threadIdx.x; i < CC * CC; i += 256) {
        int c = i / CC, cp = i % CC;
        wt[cp][c] = wo[i];
    }
    __syncthreads();
    int idx = blockIdx.x * 256 + threadIdx.x;
    int c = idx % CC;
    int t = idx / CC;
    const float* ar = att + (size_t)t * CC;
    float s = bo[c];
#pragma unroll 8
    for (int cp = 0; cp < CC; ++cp) s += ar[cp] * wt[cp][c];
    out[idx] = s;
}

extern "C" void kernel_launch(void* const* d_in, const int* in_sizes, int n_in,
                              void* d_out, int out_size, void* d_ws, size_t ws_size,
                              hipStream_t stream) {
    const float* x     = (const float*)d_in[0];
    const float* sg    = (const float*)d_in[1];
    const float* wq    = (const float*)d_in[2];
    const float* bnq_g = (const float*)d_in[3];
    const float* bnq_b = (const float*)d_in[4];
    const float* bnq_m = (const float*)d_in[5];
    const float* bnq_v = (const float*)d_in[6];
    const float* wk    = (const float*)d_in[7];
    const float* bnk_g = (const float*)d_in[8];
    const float* bnk_b = (const float*)d_in[9];
    const float* bnk_m = (const float*)d_in[10];
    const float* bnk_v = (const float*)d_in[11];
    const float* wv    = (const float*)d_in[12];
    const float* wo    = (const float*)d_in[13];
    const float* bo    = (const float*)d_in[14];

    float* ws = (float*)d_ws;
    float* wq_eff = ws + WS_WQ;
    float* wk_eff = ws + WS_WK;
    float* wv_t   = ws + WS_WV;
    float* bias_q = ws + WS_BQ;
    float* bias_k = ws + WS_BK;
    float* Qw     = ws + WS_Q;
    float* Kw     = ws + WS_K;
    float* Vw     = ws + WS_V;
    float* attw   = ws + WS_ATT;

    prep_w<<<dim3(CC), dim3(128), 0, stream>>>(wq, bnq_g, bnq_b, bnq_m, bnq_v, wq_eff, bias_q);
    prep_w<<<dim3(CC), dim3(128), 0, stream>>>(wk, bnk_g, bnk_b, bnk_m, bnk_v, wk_eff, bias_k);
    prep_v<<<dim3(CC), dim3(128), 0, stream>>>(wv, wv_t);

    qkv_conv<<<dim3(DEPTH / 2, BB), dim3(96, 2), 0, stream>>>(
        x, wq_eff, wk_eff, wv_t, bias_q, bias_k, Qw, Kw, Vw);

    attn_kernel<<<dim3(NN / 128, NHH, BB), dim3(128), 0, stream>>>(Qw, Kw, Vw, sg, attw);

    proj_kernel<<<dim3((BB * NN * CC) / 256), dim3(256), 0, stream>>>(attw, wo, bo, (float*)d_out);
}

// Round 2
// 771.332 us; speedup vs baseline: 1.6440x; 1.6440x over previous
//
#include <hip/hip_runtime.h>
#include <hip/hip_bf16.h>

#define BB 4
#define DEPTH 160
#define CC 96
#define NN 2560          // DEPTH*16
#define NHH 4
#define HD 24
#define THETA 0.6f
#define BN_EPS 1e-5f

typedef __attribute__((ext_vector_type(4))) float f32x4;
typedef __attribute__((ext_vector_type(8))) short s16x8;
typedef __attribute__((ext_vector_type(4))) short s16x4;

// ---------------------------------------------------------------------------
// Workspace layout (float slots):
//   wq_eff : 27*96*96 = 248832   [tap][oc][ic], BN scale folded, TCDC-corrected center tap
//   wk_eff : 248832
//   bias_q : 96, bias_k : 96
//   att    : 983040  (fp32, [b][n][96])
//   Qb     : 655360  (bf16 [bh][n][32], dims 24..31 zero, scaled by log2e/sg)
//   Kb     : 655360  (bf16 [bh][n][32], dims 24..31 zero)
//   Vtp    : 655360  (bf16 [bh][32][n], transposed + pi-permuted within 64-token tiles)
// total 3,446,976 floats = 13.8 MB
// ---------------------------------------------------------------------------
#define WS_WQ   0
#define WS_WK   248832
#define WS_BQ   497664
#define WS_BK   497760
#define WS_ATT  497856
#define WS_QB   1480896
#define WS_KB   2136256
#define WS_VT   2791616

__device__ __forceinline__ short f2bf(float f) {
    unsigned u = __float_as_uint(f);
    u += 0x7fffu + ((u >> 16) & 1u);
    return (short)(u >> 16);
}

// Fold TCDC center-tap correction + BN scale into conv weights; layout [tap][oc][ic].
__global__ void prep_w(const float* __restrict__ w, const float* __restrict__ gamma,
                       const float* __restrict__ beta, const float* __restrict__ mean,
                       const float* __restrict__ var, float* __restrict__ w_eff,
                       float* __restrict__ bias) {
    int oc = blockIdx.x;
    int ic = threadIdx.x;
    if (ic >= CC) return;
    float scale = gamma[oc] * rsqrtf(var[oc] + BN_EPS);
    if (ic == 0) bias[oc] = beta[oc] - mean[oc] * scale;
    const float* wp = w + (oc * CC + ic) * 27;
    float kdiff = 0.f;
#pragma unroll
    for (int t = 0; t < 9; ++t) kdiff += wp[t] + wp[18 + t];
#pragma unroll
    for (int t = 0; t < 27; ++t) {
        float v = wp[t];
        if (t == 13) v -= THETA * kdiff;     // center tap (1,1,1)
        w_eff[(size_t)t * (CC * CC) + oc * CC + ic] = v * scale;
    }
}

// One block = one depth slice: (96 oc, 4 spatial rows), each thread 4 spatial cols.
__global__ __launch_bounds__(384) void qkv_conv(
        const float* __restrict__ x, const float* __restrict__ wq_eff,
        const float* __restrict__ wk_eff, const float* __restrict__ wv,
        const float* __restrict__ bias_q, const float* __restrict__ bias_k,
        const float* __restrict__ sgp,
        short* __restrict__ Qb, short* __restrict__ Kb, short* __restrict__ Vtp) {
    __shared__ float xs[3 * 16 * CC];   // slices d-1,d,d+1  (18 KB)
    const int b = blockIdx.y;
    const int d = blockIdx.x;
    const int oc = threadIdx.x;         // 0..95
    const int y  = threadIdx.y;         // 0..3  (spatial row h)
    const int tid = y * 96 + oc;

    for (int i = tid; i < 3 * 16 * CC; i += 384) {
        int ic = i % CC;
        int r  = i / CC;
        int p  = r % 16;
        int s  = r / 16;
        int dg = d - 1 + s;
        xs[i] = (dg >= 0 && dg < DEPTH) ? x[((size_t)b * NN + dg * 16 + p) * CC + ic] : 0.f;
    }
    __syncthreads();

    float aq[4] = {0.f, 0.f, 0.f, 0.f};
    float ak[4] = {0.f, 0.f, 0.f, 0.f};
    float av[4] = {0.f, 0.f, 0.f, 0.f};

#pragma unroll
    for (int kd = 0; kd < 3; ++kd) {
        const float* xsl = xs + kd * (16 * CC);
#pragma unroll
        for (int kh = 0; kh < 3; ++kh) {
            const int hh = y + kh - 1;
            if (hh < 0 || hh > 3) continue;          // runtime, divergent-ok
            const float* xrow = xsl + hh * (4 * CC);
#pragma unroll
            for (int kw = 0; kw < 3; ++kw) {
                const int tap = kd * 9 + kh * 3 + kw;
                const float* wqp = wq_eff + (size_t)tap * (CC * CC) + oc * CC;
                const float* wkp = wk_eff + (size_t)tap * (CC * CC) + oc * CC;
#pragma unroll 2
                for (int icb = 0; icb < CC; icb += 4) {
                    f32x4 wq4 = *(const f32x4*)(wqp + icb);
                    f32x4 wk4 = *(const f32x4*)(wkp + icb);
#pragma unroll
                    for (int w = 0; w < 4; ++w) {
                        const int ww = w + kw - 1;
                        if (ww < 0 || ww > 3) continue;   // compile-time
                        f32x4 xv = *(const f32x4*)(xrow + ww * CC + icb);
#pragma unroll
                        for (int e = 0; e < 4; ++e) {
                            aq[w] += wq4[e] * xv[e];
                            ak[w] += wk4[e] * xv[e];
                        }
                    }
                }
            }
        }
    }
    // 1x1x1 V conv, center slice
    {
        const float* xrow = xs + 1 * (16 * CC) + y * (4 * CC);
#pragma unroll 2
        for (int icb = 0; icb < CC; icb += 4) {
            f32x4 wv4 = *(const f32x4*)(wv + oc * CC + icb);
#pragma unroll
            for (int w = 0; w < 4; ++w) {
                f32x4 xv = *(const f32x4*)(xrow + w * CC + icb);
#pragma unroll
                for (int e = 0; e < 4; ++e) av[w] += wv4[e] * xv[e];
            }
        }
    }

    const float bq = bias_q[oc], bk = bias_k[oc];
    const float qs = 1.4426950408889634f / sgp[0];    // log2e / sharp_gradient
    const int hhead = oc / 24, hd = oc % 24;
#pragma unroll
    for (int w = 0; w < 4; ++w) {
        const int n = d * 16 + y * 4 + w;
        const size_t tq = ((size_t)(b * NHH + hhead) * NN + n) * 32 + hd;
        Qb[tq] = f2bf((aq[w] + bq) * qs);
        Kb[tq] = f2bf(ak[w] + bk);
        const int pn = (n & ~63) | ((n & 15) << 2) | ((n >> 4) & 3);  // pi-permute
        Vtp[(size_t)(b * NHH + hhead) * (32 * NN) + (size_t)hd * NN + pn] = f2bf(av[w]);
    }
    if (oc < 32) {   // zero the pad dims 24..31 of Q,K (contracted in MFMA -> must be 0)
        const int h2 = oc >> 3, hd2 = 24 + (oc & 7);
#pragma unroll
        for (int w = 0; w < 4; ++w) {
            const int n = d * 16 + y * 4 + w;
            const size_t t = ((size_t)(b * NHH + h2) * NN + n) * 32 + hd2;
            Qb[t] = 0; Kb[t] = 0;
        }
    }
}

// MFMA flash attention: 1 wave per block, 16 q-rows per wave, 64-key tiles.
#define SOFTMAX_R(r, mr, lr) {                                                  \
    float vmx = fmaxf(fmaxf(sf0[r], sf1[r]), fmaxf(sf2[r], sf3[r]));            \
    vmx = fmaxf(vmx, __shfl_xor(vmx, 1));                                       \
    vmx = fmaxf(vmx, __shfl_xor(vmx, 2));                                       \
    vmx = fmaxf(vmx, __shfl_xor(vmx, 4));                                       \
    vmx = fmaxf(vmx, __shfl_xor(vmx, 8));                                       \
    float mn = fmaxf(mr, vmx);                                                  \
    float sc = exp2f(mr - mn);                                                  \
    mr = mn; lr *= sc;                                                          \
    of0[r] *= sc; of1[r] *= sc;                                                 \
    float p0 = exp2f(sf0[r] - mn), p1 = exp2f(sf1[r] - mn);                     \
    float p2 = exp2f(sf2[r] - mn), p3 = exp2f(sf3[r] - mn);                     \
    lr += (p0 + p1) + (p2 + p3);                                                \
    s16x4 pw = { f2bf(p0), f2bf(p1), f2bf(p2), f2bf(p3) };                      \
    *(s16x4*)&P_lds[(4 * g + r) * 64 + ((4 * j) ^ (g << 3))] = pw;              \
}

__global__ __launch_bounds__(64) void attn_kernel(
        const short* __restrict__ Qb, const short* __restrict__ Kb,
        const short* __restrict__ Vtp, float* __restrict__ att) {
    __shared__ short P_lds[16 * 64];   // [q][pos] bf16, XOR-swizzled (2 KB)
    const int b = blockIdx.z, h = blockIdx.y;
    const int bh = b * NHH + h;
    const int q0 = blockIdx.x * 16;
    const int l = threadIdx.x;
    const int j = l & 15, g = l >> 4;

    const short* Qp = Qb + ((size_t)bh * NN + q0 + j) * 32 + 8 * g;
    s16x8 qf = *(const s16x8*)Qp;                      // A-frag: Q rows, scaled
    const short* Kbase = Kb + (size_t)bh * NN * 32;
    const short* Vbase = Vtp + (size_t)bh * 32 * NN;

    f32x4 of0 = {0.f, 0.f, 0.f, 0.f};                  // O cols d=0..15
    f32x4 of1 = {0.f, 0.f, 0.f, 0.f};                  // O cols d=16..23 (+pad)
    float m0 = -1e30f, m1 = -1e30f, m2 = -1e30f, m3 = -1e30f;
    float l0 = 0.f, l1 = 0.f, l2 = 0.f, l3 = 0.f;
    const f32x4 z = {0.f, 0.f, 0.f, 0.f};

    for (int t0 = 0; t0 < NN; t0 += 64) {
        const short* kp = Kbase + (size_t)(t0 + j) * 32 + 8 * g;
        s16x8 kf0 = *(const s16x8*)(kp);               // B-frags: 4 key-tiles
        s16x8 kf1 = *(const s16x8*)(kp + 512);
        s16x8 kf2 = *(const s16x8*)(kp + 1024);
        s16x8 kf3 = *(const s16x8*)(kp + 1536);
        f32x4 sf0 = __builtin_amdgcn_mfma_f32_16x16x32_bf16(qf, kf0, z, 0, 0, 0);
        f32x4 sf1 = __builtin_amdgcn_mfma_f32_16x16x32_bf16(qf, kf1, z, 0, 0, 0);
        f32x4 sf2 = __builtin_amdgcn_mfma_f32_16x16x32_bf16(qf, kf2, z, 0, 0, 0);
        f32x4 sf3 = __builtin_amdgcn_mfma_f32_16x16x32_bf16(qf, kf3, z, 0, 0, 0);

        SOFTMAX_R(0, m0, l0)
        SOFTMAX_R(1, m1, l1)
        SOFTMAX_R(2, m2, l2)
        SOFTMAX_R(3, m3, l3)

        asm volatile("s_waitcnt lgkmcnt(0)" ::: "memory");
        __builtin_amdgcn_sched_barrier(0);

        // PV: A = P (from LDS, pos-space), B = V (global, pre-permuted pos-space)
        s16x8 pa0 = *(const s16x8*)&P_lds[j * 64 + ((8 * g) ^ ((j >> 2) << 3))];
        s16x8 pa1 = *(const s16x8*)&P_lds[j * 64 + ((32 + 8 * g) ^ ((j >> 2) << 3))];
        const short* vp = Vbase + (size_t)j * NN + t0 + 8 * g;
        s16x8 vf00 = *(const s16x8*)(vp);              // d 0..15,  pos 0..31
        s16x8 vf01 = *(const s16x8*)(vp + 32);         // d 0..15,  pos 32..63
        s16x8 vf10 = *(const s16x8*)(vp + 16 * NN);    // d 16..31, pos 0..31
        s16x8 vf11 = *(const s16x8*)(vp + 16 * NN + 32);
        of0 = __builtin_amdgcn_mfma_f32_16x16x32_bf16(pa0, vf00, of0, 0, 0, 0);
        of0 = __builtin_amdgcn_mfma_f32_16x16x32_bf16(pa1, vf01, of0, 0, 0, 0);
        of1 = __builtin_amdgcn_mfma_f32_16x16x32_bf16(pa0, vf10, of1, 0, 0, 0);
        of1 = __builtin_amdgcn_mfma_f32_16x16x32_bf16(pa1, vf11, of1, 0, 0, 0);
    }

    // final row-sum reduce (16-lane groups) and store
    l0 += __shfl_xor(l0, 1); l0 += __shfl_xor(l0, 2); l0 += __shfl_xor(l0, 4); l0 += __shfl_xor(l0, 8);
    l1 += __shfl_xor(l1, 1); l1 += __shfl_xor(l1, 2); l1 += __shfl_xor(l1, 4); l1 += __shfl_xor(l1, 8);
    l2 += __shfl_xor(l2, 1); l2 += __shfl_xor(l2, 2); l2 += __shfl_xor(l2, 4); l2 += __shfl_xor(l2, 8);
    l3 += __shfl_xor(l3, 1); l3 += __shfl_xor(l3, 2); l3 += __shfl_xor(l3, 4); l3 += __shfl_xor(l3, 8);
    const float rl0 = 1.f / l0, rl1 = 1.f / l1, rl2 = 1.f / l2, rl3 = 1.f / l3;

    float* ob = att + ((size_t)b * NN + q0 + 4 * g) * CC + h * HD;
    ob[0 * CC + j] = of0[0] * rl0;
    ob[1 * CC + j] = of0[1] * rl1;
    ob[2 * CC + j] = of0[2] * rl2;
    ob[3 * CC + j] = of0[3] * rl3;
    if (j < 8) {
        ob[0 * CC + 16 + j] = of1[0] * rl0;
        ob[1 * CC + 16 + j] = of1[1] * rl1;
        ob[2 * CC + 16 + j] = of1[2] * rl2;
        ob[3 * CC + 16 + j] = of1[3] * rl3;
    }
}

// out[t,c] = bo[c] + sum_cp att[t,cp] * wo[c,cp]
__global__ __launch_bounds__(256) void proj_kernel(
        const float* __restrict__ att, const float* __restrict__ wo,
        const float* __restrict__ bo, float* __restrict__ out) {
    __shared__ float wt[CC][CC + 1];   // wt[cp][c] = wo[c][cp], padded
    for (int i = threadIdx.x; i < CC * CC; i += 256) {
        int c = i / CC, cp = i % CC;
        wt[cp][c] = wo[i];
    }
    __syncthreads();
    int idx = blockIdx.x * 256 + threadIdx.x;
    int c = idx % CC;
    int t = idx / CC;
    const float* ar = att + (size_t)t * CC;
    float s = bo[c];
#pragma unroll 8
    for (int cp = 0; cp < CC; ++cp) s += ar[cp] * wt[cp][c];
    out[idx] = s;
}

extern "C" void kernel_launch(void* const* d_in, const int* in_sizes, int n_in,
                              void* d_out, int out_size, void* d_ws, size_t ws_size,
                              hipStream_t stream) {
    const float* x     = (const float*)d_in[0];
    const float* sg    = (const float*)d_in[1];
    const float* wq    = (const float*)d_in[2];
    const float* bnq_g = (const float*)d_in[3];
    const float* bnq_b = (const float*)d_in[4];
    const float* bnq_m = (const float*)d_in[5];
    const float* bnq_v = (const float*)d_in[6];
    const float* wk    = (const float*)d_in[7];
    const float* bnk_g = (const float*)d_in[8];
    const float* bnk_b = (const float*)d_in[9];
    const float* bnk_m = (const float*)d_in[10];
    const float* bnk_v = (const float*)d_in[11];
    const float* wv    = (const float*)d_in[12];
    const float* wo    = (const float*)d_in[13];
    const float* bo    = (const float*)d_in[14];

    float* ws = (float*)d_ws;
    float* wq_eff = ws + WS_WQ;
    float* wk_eff = ws + WS_WK;
    float* bias_q = ws + WS_BQ;
    float* bias_k = ws + WS_BK;
    float* attw   = ws + WS_ATT;
    short* Qb     = (short*)(ws + WS_QB);
    short* Kb     = (short*)(ws + WS_KB);
    short* Vtp    = (short*)(ws + WS_VT);

    prep_w<<<dim3(CC), dim3(128), 0, stream>>>(wq, bnq_g, bnq_b, bnq_m, bnq_v, wq_eff, bias_q);
    prep_w<<<dim3(CC), dim3(128), 0, stream>>>(wk, bnk_g, bnk_b, bnk_m, bnk_v, wk_eff, bias_k);

    qkv_conv<<<dim3(DEPTH, BB), dim3(96, 4), 0, stream>>>(
        x, wq_eff, wk_eff, wv, bias_q, bias_k, sg, Qb, Kb, Vtp);

    attn_kernel<<<dim3(NN / 16, NHH, BB), dim3(64), 0, stream>>>(Qb, Kb, Vtp, attw);

    proj_kernel<<<dim3((BB * NN * CC) / 256), dim3(256), 0, stream>>>(attw, wo, bo, (float*)d_out);
}

// Round 3
// 191.479 us; speedup vs baseline: 6.6224x; 4.0283x over previous
//
#include <hip/hip_runtime.h>
#include <hip/hip_bf16.h>

#define BB 4
#define DEPTH 160
#define CC 96
#define NN 2560          // DEPTH*16
#define NHH 4
#define HD 24
#define THETA 0.6f
#define BN_EPS 1e-5f

typedef __attribute__((ext_vector_type(4))) float f32x4;
typedef __attribute__((ext_vector_type(8))) short s16x8;
typedef __attribute__((ext_vector_type(4))) short s16x4;

// ---------------------------------------------------------------------------
// Workspace layout (float slots):
//   wq_b  : bf16 [tap][oc][ic] 27*96*96 shorts  -> 124416 slots
//   wk_b  : 124416
//   wv_b  : bf16 [oc][ic] 9216 shorts           -> 4608
//   bias_q: 96, bias_k: 96 (fp32)
//   att   : fp32 [b][n][96]                     -> 983040
//   Qb    : bf16 [bh][n][32] (hd 24..31 zeroed) -> 655360
//   Kb    : bf16 [bh][n][32]                    -> 655360
//   Vtp   : bf16 [bh][32][n] transposed+pi-permuted (hd 24..31 never read as k) -> 655360
// total ~12.9 MB
// ---------------------------------------------------------------------------
#define WS_WQ   0
#define WS_WK   124416
#define WS_WV   248832
#define WS_BQ   253440
#define WS_BK   253536
#define WS_ATT  253632
#define WS_QB   1236672
#define WS_KB   1892032
#define WS_VT   2547392

__device__ __forceinline__ short f2bf(float f) {
    unsigned u = __float_as_uint(f);
    u += 0x7fffu + ((u >> 16) & 1u);
    return (short)(u >> 16);
}

// Fold TCDC center-tap correction + BN scale into conv weights; bf16 [tap][oc][ic].
__global__ void prep_w(const float* __restrict__ w, const float* __restrict__ gamma,
                       const float* __restrict__ beta, const float* __restrict__ mean,
                       const float* __restrict__ var, short* __restrict__ w_eff,
                       float* __restrict__ bias) {
    int oc = blockIdx.x;
    int ic = threadIdx.x;
    if (ic >= CC) return;
    float scale = gamma[oc] * rsqrtf(var[oc] + BN_EPS);
    if (ic == 0) bias[oc] = beta[oc] - mean[oc] * scale;
    const float* wp = w + (oc * CC + ic) * 27;
    float kdiff = 0.f;
#pragma unroll
    for (int t = 0; t < 9; ++t) kdiff += wp[t] + wp[18 + t];
#pragma unroll
    for (int t = 0; t < 27; ++t) {
        float v = wp[t];
        if (t == 13) v -= THETA * kdiff;     // center tap (1,1,1)
        w_eff[t * (CC * CC) + oc * CC + ic] = f2bf(v * scale);
    }
}

__global__ void prep_v(const float* __restrict__ wv, short* __restrict__ wv_b) {
    int i = blockIdx.x * 512 + threadIdx.x;
    if (i < CC * CC) wv_b[i] = f2bf(wv[i]);
}

// MFMA im2col conv. Block = 2 depth slices, 8 waves = (qk) x (oc-half) x (slice).
// LDS: 4 staged slices (with zero-filled depth halo) + a zero row for spatial OOB.
__global__ __launch_bounds__(512, 4) void qkv_conv(
        const float* __restrict__ x, const short* __restrict__ wq_b,
        const short* __restrict__ wk_b, const short* __restrict__ wv_b,
        const float* __restrict__ bias_q, const float* __restrict__ bias_k,
        const float* __restrict__ sgp,
        short* __restrict__ Qb, short* __restrict__ Kb, short* __restrict__ Vtp) {
    __shared__ __align__(16) short xs[65 * 104];   // 64 rows + zero row, padded stride 104
    const int b = blockIdx.y;
    const int d0 = blockIdx.x * 2;
    const int tid = threadIdx.x;

    // stage: 4 slices (d0-1 .. d0+2), f32 -> bf16, 4-elem chunks
#pragma unroll
    for (int k = 0; k < 3; ++k) {
        int c = tid + k * 512;              // 1536 chunks
        int row = c / 24, ic0 = (c % 24) * 4;
        int dg = d0 - 1 + (row >> 4), pos = row & 15;
        s16x4 o = {0, 0, 0, 0};
        if (dg >= 0 && dg < DEPTH) {
            f32x4 v = *(const f32x4*)(x + ((size_t)(b * NN + dg * 16 + pos)) * CC + ic0);
            o[0] = f2bf(v[0]); o[1] = f2bf(v[1]); o[2] = f2bf(v[2]); o[3] = f2bf(v[3]);
        }
        *(s16x4*)&xs[row * 104 + ic0] = o;
    }
    if (tid < 26) *(s16x4*)&xs[64 * 104 + tid * 4] = (s16x4){0, 0, 0, 0};
    __syncthreads();

    const int w  = tid >> 6, l = tid & 63;
    const int qk = w >> 2, och = (w >> 1) & 1, t = w & 1;
    const int j  = l & 15, g = l >> 4;
    const int oc0 = och * 48;
    const int hj = j >> 2, wj = j & 3;

    const short* wp = qk ? wk_b : wq_b;
    const short* wlane  = wp   + (oc0 + j) * CC + 8 * g;
    const short* wvlane = wv_b + (oc0 + j) * CC + 8 * g;

    f32x4 acc0 = {0,0,0,0}, acc1 = {0,0,0,0}, acc2 = {0,0,0,0};
    f32x4 av0  = {0,0,0,0}, av1  = {0,0,0,0}, av2  = {0,0,0,0};

#pragma unroll
    for (int kd = 0; kd < 3; ++kd)
#pragma unroll
    for (int kh = 0; kh < 3; ++kh)
#pragma unroll
    for (int kw = 0; kw < 3; ++kw) {
        const int tap = kd * 9 + kh * 3 + kw;
        const int hh = hj + kh - 1, ww = wj + kw - 1;
        const bool valid = ((unsigned)hh < 4u) && ((unsigned)ww < 4u);
        const int row = valid ? ((t + kd) * 16 + hh * 4 + ww) : 64;   // 64 = zero row
        const short* xrow = &xs[row * 104 + 8 * g];
#pragma unroll
        for (int icb = 0; icb < 3; ++icb) {
            s16x8 af = *(const s16x8*)(xrow + icb * 32);
            const short* wt = wlane + tap * (CC * CC) + icb * 32;
            acc0 = __builtin_amdgcn_mfma_f32_16x16x32_bf16(af, *(const s16x8*)(wt),           acc0, 0, 0, 0);
            acc1 = __builtin_amdgcn_mfma_f32_16x16x32_bf16(af, *(const s16x8*)(wt + 16 * CC), acc1, 0, 0, 0);
            acc2 = __builtin_amdgcn_mfma_f32_16x16x32_bf16(af, *(const s16x8*)(wt + 32 * CC), acc2, 0, 0, 0);
            if (tap == 13 && qk == 0) {   // V rides the center tap's A-frag (Q-waves only)
                const short* wtv = wvlane + icb * 32;
                av0 = __builtin_amdgcn_mfma_f32_16x16x32_bf16(af, *(const s16x8*)(wtv),           av0, 0, 0, 0);
                av1 = __builtin_amdgcn_mfma_f32_16x16x32_bf16(af, *(const s16x8*)(wtv + 16 * CC), av1, 0, 0, 0);
                av2 = __builtin_amdgcn_mfma_f32_16x16x32_bf16(af, *(const s16x8*)(wtv + 32 * CC), av2, 0, 0, 0);
            }
        }
    }

    // epilogue: C[col = oc0+OCT*16+j, row(token) = 4g+r]
    const int n0 = (d0 + t) * 16 + 4 * g;
    const float qs = 1.4426950408889634f / sgp[0];

#define EPI_QK(accv, OCT) {                                                     \
    const int oc = oc0 + OCT * 16 + j;                                          \
    const int h = oc / HD, hd = oc % HD;                                        \
    const float bb_ = qk ? bias_k[oc] : bias_q[oc];                             \
    short* Ob = (qk ? Kb : Qb) + ((size_t)(b * NHH + h) * NN + n0) * 32 + hd;   \
    _Pragma("unroll")                                                           \
    for (int r = 0; r < 4; ++r) {                                               \
        float v_ = accv[r] + bb_;                                               \
        if (!qk) v_ *= qs;                                                      \
        Ob[r * 32] = f2bf(v_);                                                  \
    }                                                                           \
}
    EPI_QK(acc0, 0) EPI_QK(acc1, 1) EPI_QK(acc2, 2)

    if (qk == 0) {
        // V epilogue: Vtp[bh][hd][pi(n)]
#define EPI_V(avv, OCT) {                                                       \
    const int oc = oc0 + OCT * 16 + j;                                          \
    const int h = oc / HD, hd = oc % HD;                                        \
    short* Vb = Vtp + (size_t)(b * NHH + h) * (32 * NN) + (size_t)hd * NN;      \
    _Pragma("unroll")                                                           \
    for (int r = 0; r < 4; ++r) {                                               \
        int n = n0 + r;                                                         \
        int pn = (n & ~63) | ((n & 15) << 2) | ((n >> 4) & 3);                  \
        Vb[pn] = f2bf(avv[r]);                                                  \
    }                                                                           \
}
        EPI_V(av0, 0) EPI_V(av1, 1) EPI_V(av2, 2)

        // zero the k-pad hd 24..31 of Qb,Kb (read by attn's g==3 fragments)
        const int h = 2 * och + (g & 1);
        const int n = (d0 + t) * 16 + j;
        short* Pp = ((g >> 1) ? Kb : Qb) + ((size_t)(b * NHH + h) * NN + n) * 32 + 24;
        *(s16x8*)Pp = (s16x8){0, 0, 0, 0, 0, 0, 0, 0};
    }
}

// MFMA flash attention: 1 wave per block, 16 q-rows per wave, 64-key tiles.
#define SOFTMAX_R(r, mr, lr) {                                                  \
    float vmx = fmaxf(fmaxf(sf0[r], sf1[r]), fmaxf(sf2[r], sf3[r]));            \
    vmx = fmaxf(vmx, __shfl_xor(vmx, 1));                                       \
    vmx = fmaxf(vmx, __shfl_xor(vmx, 2));                                       \
    vmx = fmaxf(vmx, __shfl_xor(vmx, 4));                                       \
    vmx = fmaxf(vmx, __shfl_xor(vmx, 8));                                       \
    float mn = fmaxf(mr, vmx);                                                  \
    float sc = exp2f(mr - mn);                                                  \
    mr = mn; lr *= sc;                                                          \
    of0[r] *= sc; of1[r] *= sc;                                                 \
    float p0 = exp2f(sf0[r] - mn), p1 = exp2f(sf1[r] - mn);                     \
    float p2 = exp2f(sf2[r] - mn), p3 = exp2f(sf3[r] - mn);                     \
    lr += (p0 + p1) + (p2 + p3);                                                \
    s16x4 pw = { f2bf(p0), f2bf(p1), f2bf(p2), f2bf(p3) };                      \
    *(s16x4*)&P_lds[(4 * g + r) * 64 + ((4 * j) ^ (g << 3))] = pw;              \
}

__global__ __launch_bounds__(64) void attn_kernel(
        const short* __restrict__ Qb, const short* __restrict__ Kb,
        const short* __restrict__ Vtp, float* __restrict__ att) {
    __shared__ short P_lds[16 * 64];   // [q][pos] bf16, XOR-swizzled (2 KB)
    const int b = blockIdx.z, h = blockIdx.y;
    const int bh = b * NHH + h;
    const int q0 = blockIdx.x * 16;
    const int l = threadIdx.x;
    const int j = l & 15, g = l >> 4;

    const short* Qp = Qb + ((size_t)bh * NN + q0 + j) * 32 + 8 * g;
    s16x8 qf = *(const s16x8*)Qp;                      // A-frag: Q rows, scaled
    const short* Kbase = Kb + (size_t)bh * NN * 32;
    const short* Vbase = Vtp + (size_t)bh * 32 * NN;

    f32x4 of0 = {0.f, 0.f, 0.f, 0.f};                  // O cols d=0..15
    f32x4 of1 = {0.f, 0.f, 0.f, 0.f};                  // O cols d=16..23 (+pad)
    float m0 = -1e30f, m1 = -1e30f, m2 = -1e30f, m3 = -1e30f;
    float l0 = 0.f, l1 = 0.f, l2 = 0.f, l3 = 0.f;
    const f32x4 z = {0.f, 0.f, 0.f, 0.f};

    for (int t0 = 0; t0 < NN; t0 += 64) {
        const short* kp = Kbase + (size_t)(t0 + j) * 32 + 8 * g;
        s16x8 kf0 = *(const s16x8*)(kp);               // B-frags: 4 key-tiles
        s16x8 kf1 = *(const s16x8*)(kp + 512);
        s16x8 kf2 = *(const s16x8*)(kp + 1024);
        s16x8 kf3 = *(const s16x8*)(kp + 1536);
        f32x4 sf0 = __builtin_amdgcn_mfma_f32_16x16x32_bf16(qf, kf0, z, 0, 0, 0);
        f32x4 sf1 = __builtin_amdgcn_mfma_f32_16x16x32_bf16(qf, kf1, z, 0, 0, 0);
        f32x4 sf2 = __builtin_amdgcn_mfma_f32_16x16x32_bf16(qf, kf2, z, 0, 0, 0);
        f32x4 sf3 = __builtin_amdgcn_mfma_f32_16x16x32_bf16(qf, kf3, z, 0, 0, 0);

        SOFTMAX_R(0, m0, l0)
        SOFTMAX_R(1, m1, l1)
        SOFTMAX_R(2, m2, l2)
        SOFTMAX_R(3, m3, l3)

        asm volatile("s_waitcnt lgkmcnt(0)" ::: "memory");
        __builtin_amdgcn_sched_barrier(0);

        // PV: A = P (from LDS, pos-space), B = V (global, pre-permuted pos-space)
        s16x8 pa0 = *(const s16x8*)&P_lds[j * 64 + ((8 * g) ^ ((j >> 2) << 3))];
        s16x8 pa1 = *(const s16x8*)&P_lds[j * 64 + ((32 + 8 * g) ^ ((j >> 2) << 3))];
        const short* vp = Vbase + (size_t)j * NN + t0 + 8 * g;
        s16x8 vf00 = *(const s16x8*)(vp);              // d 0..15,  pos 0..31
        s16x8 vf01 = *(const s16x8*)(vp + 32);         // d 0..15,  pos 32..63
        s16x8 vf10 = *(const s16x8*)(vp + 16 * NN);    // d 16..31, pos 0..31
        s16x8 vf11 = *(const s16x8*)(vp + 16 * NN + 32);
        of0 = __builtin_amdgcn_mfma_f32_16x16x32_bf16(pa0, vf00, of0, 0, 0, 0);
        of0 = __builtin_amdgcn_mfma_f32_16x16x32_bf16(pa1, vf01, of0, 0, 0, 0);
        of1 = __builtin_amdgcn_mfma_f32_16x16x32_bf16(pa0, vf10, of1, 0, 0, 0);
        of1 = __builtin_amdgcn_mfma_f32_16x16x32_bf16(pa1, vf11, of1, 0, 0, 0);
    }

    // final row-sum reduce (16-lane groups) and store
    l0 += __shfl_xor(l0, 1); l0 += __shfl_xor(l0, 2); l0 += __shfl_xor(l0, 4); l0 += __shfl_xor(l0, 8);
    l1 += __shfl_xor(l1, 1); l1 += __shfl_xor(l1, 2); l1 += __shfl_xor(l1, 4); l1 += __shfl_xor(l1, 8);
    l2 += __shfl_xor(l2, 1); l2 += __shfl_xor(l2, 2); l2 += __shfl_xor(l2, 4); l2 += __shfl_xor(l2, 8);
    l3 += __shfl_xor(l3, 1); l3 += __shfl_xor(l3, 2); l3 += __shfl_xor(l3, 4); l3 += __shfl_xor(l3, 8);
    const float rl0 = 1.f / l0, rl1 = 1.f / l1, rl2 = 1.f / l2, rl3 = 1.f / l3;

    float* ob = att + ((size_t)b * NN + q0 + 4 * g) * CC + h * HD;
    ob[0 * CC + j] = of0[0] * rl0;
    ob[1 * CC + j] = of0[1] * rl1;
    ob[2 * CC + j] = of0[2] * rl2;
    ob[3 * CC + j] = of0[3] * rl3;
    if (j < 8) {
        ob[0 * CC + 16 + j] = of1[0] * rl0;
        ob[1 * CC + 16 + j] = of1[1] * rl1;
        ob[2 * CC + 16 + j] = of1[2] * rl2;
        ob[3 * CC + 16 + j] = of1[3] * rl3;
    }
}

// out[t,c] = bo[c] + sum_cp att[t,cp] * wo[c,cp]
__global__ __launch_bounds__(256) void proj_kernel(
        const float* __restrict__ att, const float* __restrict__ wo,
        const float* __restrict__ bo, float* __restrict__ out) {
    __shared__ float wt[CC][CC + 1];   // wt[cp][c] = wo[c][cp], padded
    for (int i = threadIdx.x; i < CC * CC; i += 256) {
        int c = i / CC, cp = i % CC;
        wt[cp][c] = wo[i];
    }
    __syncthreads();
    int idx = blockIdx.x * 256 + threadIdx.x;
    int c = idx % CC;
    int t = idx / CC;
    const float* ar = att + (size_t)t * CC;
    float s = bo[c];
#pragma unroll 8
    for (int cp = 0; cp < CC; ++cp) s += ar[cp] * wt[cp][c];
    out[idx] = s;
}

extern "C" void kernel_launch(void* const* d_in, const int* in_sizes, int n_in,
                              void* d_out, int out_size, void* d_ws, size_t ws_size,
                              hipStream_t stream) {
    const float* x     = (const float*)d_in[0];
    const float* sg    = (const float*)d_in[1];
    const float* wq    = (const float*)d_in[2];
    const float* bnq_g = (const float*)d_in[3];
    const float* bnq_b = (const float*)d_in[4];
    const float* bnq_m = (const float*)d_in[5];
    const float* bnq_v = (const float*)d_in[6];
    const float* wk    = (const float*)d_in[7];
    const float* bnk_g = (const float*)d_in[8];
    const float* bnk_b = (const float*)d_in[9];
    const float* bnk_m = (const float*)d_in[10];
    const float* bnk_v = (const float*)d_in[11];
    const float* wv    = (const float*)d_in[12];
    const float* wo    = (const float*)d_in[13];
    const float* bo    = (const float*)d_in[14];

    float* ws = (float*)d_ws;
    short* wq_b   = (short*)(ws + WS_WQ);
    short* wk_b   = (short*)(ws + WS_WK);
    short* wv_b   = (short*)(ws + WS_WV);
    float* bias_q = ws + WS_BQ;
    float* bias_k = ws + WS_BK;
    float* attw   = ws + WS_ATT;
    short* Qb     = (short*)(ws + WS_QB);
    short* Kb     = (short*)(ws + WS_KB);
    short* Vtp    = (short*)(ws + WS_VT);

    prep_w<<<dim3(CC), dim3(128), 0, stream>>>(wq, bnq_g, bnq_b, bnq_m, bnq_v, wq_b, bias_q);
    prep_w<<<dim3(CC), dim3(128), 0, stream>>>(wk, bnk_g, bnk_b, bnk_m, bnk_v, wk_b, bias_k);
    prep_v<<<dim3(18), dim3(512), 0, stream>>>(wv, wv_b);

    qkv_conv<<<dim3(DEPTH / 2, BB), dim3(512), 0, stream>>>(
        x, wq_b, wk_b, wv_b, bias_q, bias_k, sg, Qb, Kb, Vtp);

    attn_kernel<<<dim3(NN / 16, NHH, BB), dim3(64), 0, stream>>>(Qb, Kb, Vtp, attw);

    proj_kernel<<<dim3((BB * NN * CC) / 256), dim3(256), 0, stream>>>(attw, wo, bo, (float*)d_out);
}

// Round 4
// 139.917 us; speedup vs baseline: 9.0629x; 1.3685x over previous
//
#include <hip/hip_runtime.h>
#include <hip/hip_bf16.h>

#define BB 4
#define DEPTH 160
#define CC 96
#define NN 2560          // DEPTH*16
#define NHH 4
#define HD 24
#define THETA 0.6f
#define BN_EPS 1e-5f

typedef __attribute__((ext_vector_type(4))) float f32x4;
typedef __attribute__((ext_vector_type(8))) short s16x8;
typedef __attribute__((ext_vector_type(4))) short s16x4;

// ---------------------------------------------------------------------------
// Workspace layout (float slots):
//   wq_b  : bf16 [tap][oc][ic] 27*96*96 shorts  -> 124416 slots
//   wk_b  : 124416
//   wv_b  : bf16 [oc][ic] 9216 shorts           -> 4608
//   bias_q: 96, bias_k: 96 (fp32)
//   att   : fp32 [b][n][96]                     -> 983040
//   Qb    : bf16 [bh][n][32] (hd 24..31 zeroed) -> 655360
//   Kb    : bf16 [bh][n][32]                    -> 655360
//   Vtp   : bf16 [bh][32][n] transposed+pi-permuted -> 655360
// total ~12.9 MB
// ---------------------------------------------------------------------------
#define WS_WQ   0
#define WS_WK   124416
#define WS_WV   248832
#define WS_BQ   253440
#define WS_BK   253536
#define WS_ATT  253632
#define WS_QB   1236672
#define WS_KB   1892032
#define WS_VT   2547392

__device__ __forceinline__ short f2bf(float f) {
    unsigned u = __float_as_uint(f);
    u += 0x7fffu + ((u >> 16) & 1u);
    return (short)(u >> 16);
}

// full-rate VALU reduce over 16-lane rows via DPP (no LDS pipe)
#define DPPF(x, ctrl) __int_as_float(__builtin_amdgcn_update_dpp(0, __float_as_int(x), ctrl, 0xF, 0xF, true))
__device__ __forceinline__ float rmax16(float v) {
    v = fmaxf(v, DPPF(v, 0xB1));    // quad_perm(1,0,3,2)
    v = fmaxf(v, DPPF(v, 0x4E));    // quad_perm(2,3,0,1)
    v = fmaxf(v, DPPF(v, 0x124));   // row_ror:4
    v = fmaxf(v, DPPF(v, 0x128));   // row_ror:8
    return v;
}
__device__ __forceinline__ float rsum16(float v) {
    v += DPPF(v, 0xB1);
    v += DPPF(v, 0x4E);
    v += DPPF(v, 0x124);
    v += DPPF(v, 0x128);
    return v;
}

// Fold TCDC center-tap correction + BN scale into conv weights; bf16 [tap][oc][ic].
__global__ void prep_w(const float* __restrict__ w, const float* __restrict__ gamma,
                       const float* __restrict__ beta, const float* __restrict__ mean,
                       const float* __restrict__ var, short* __restrict__ w_eff,
                       float* __restrict__ bias) {
    int oc = blockIdx.x;
    int ic = threadIdx.x;
    if (ic >= CC) return;
    float scale = gamma[oc] * rsqrtf(var[oc] + BN_EPS);
    if (ic == 0) bias[oc] = beta[oc] - mean[oc] * scale;
    const float* wp = w + (oc * CC + ic) * 27;
    float kdiff = 0.f;
#pragma unroll
    for (int t = 0; t < 9; ++t) kdiff += wp[t] + wp[18 + t];
#pragma unroll
    for (int t = 0; t < 27; ++t) {
        float v = wp[t];
        if (t == 13) v -= THETA * kdiff;     // center tap (1,1,1)
        w_eff[t * (CC * CC) + oc * CC + ic] = f2bf(v * scale);
    }
}

__global__ void prep_v(const float* __restrict__ wv, short* __restrict__ wv_b) {
    int i = blockIdx.x * 512 + threadIdx.x;
    if (i < CC * CC) wv_b[i] = f2bf(wv[i]);
}

// MFMA im2col conv. Block = (2 depth slices) x (oc-half); 6 waves = qk(2) x oct(3).
// Each wave: 1 oc-tile of 16, both token-slices (B-frag reused 2x), 162 MFMA.
__global__ __launch_bounds__(384, 4) void qkv_conv(
        const float* __restrict__ x, const short* __restrict__ wq_b,
        const short* __restrict__ wk_b, const short* __restrict__ wv_b,
        const float* __restrict__ bias_q, const float* __restrict__ bias_k,
        const float* __restrict__ sgp,
        short* __restrict__ Qb, short* __restrict__ Kb, short* __restrict__ Vtp) {
    __shared__ __align__(16) short xs[65 * 104];   // 64 rows + zero row, padded stride 104
    const int b = blockIdx.y;
    const int d0 = blockIdx.x * 2;
    const int z = blockIdx.z;                       // oc-half
    const int tid = threadIdx.x;

    // stage 4 slices (d0-1 .. d0+2), f32 -> bf16
#pragma unroll
    for (int k = 0; k < 4; ++k) {
        int c = tid + k * 384;                      // 1536 chunks
        int row = c / 24, ic0 = (c % 24) * 4;
        int dg = d0 - 1 + (row >> 4), pos = row & 15;
        s16x4 o = {0, 0, 0, 0};
        if (dg >= 0 && dg < DEPTH) {
            f32x4 v = *(const f32x4*)(x + ((size_t)(b * NN + dg * 16 + pos)) * CC + ic0);
            o[0] = f2bf(v[0]); o[1] = f2bf(v[1]); o[2] = f2bf(v[2]); o[3] = f2bf(v[3]);
        }
        *(s16x4*)&xs[row * 104 + ic0] = o;
    }
    if (tid < 26) *(s16x4*)&xs[64 * 104 + tid * 4] = (s16x4){0, 0, 0, 0};
    __syncthreads();

    const int w  = tid >> 6, l = tid & 63;
    const int qk = w / 3, oct = w % 3;
    const int j  = l & 15, g = l >> 4;
    const int oc0 = z * 48 + oct * 16;
    const int hj = j >> 2, wj = j & 3;

    const short* wlane  = (qk ? wk_b : wq_b) + (oc0 + j) * CC + 8 * g;
    const short* wvlane = wv_b + (oc0 + j) * CC + 8 * g;

    f32x4 accA = {0,0,0,0}, accB = {0,0,0,0};
    f32x4 avA  = {0,0,0,0}, avB  = {0,0,0,0};

#pragma unroll
    for (int kd = 0; kd < 3; ++kd)
#pragma unroll
    for (int kh = 0; kh < 3; ++kh)
#pragma unroll
    for (int kw = 0; kw < 3; ++kw) {
        const int tap = kd * 9 + kh * 3 + kw;
        const int hh = hj + kh - 1, ww = wj + kw - 1;
        const bool valid = ((unsigned)hh < 4u) && ((unsigned)ww < 4u);
        const int rA = valid ? (kd * 16 + hh * 4 + ww) : 64;       // slice t=0
        const int rB = valid ? ((1 + kd) * 16 + hh * 4 + ww) : 64; // slice t=1
        const short* xrA = &xs[rA * 104 + 8 * g];
        const short* xrB = &xs[rB * 104 + 8 * g];
        const short* wt = wlane + tap * (CC * CC);
#pragma unroll
        for (int icb = 0; icb < 3; ++icb) {
            s16x8 bfr = *(const s16x8*)(wt + icb * 32);
            s16x8 afA = *(const s16x8*)(xrA + icb * 32);
            s16x8 afB = *(const s16x8*)(xrB + icb * 32);
            accA = __builtin_amdgcn_mfma_f32_16x16x32_bf16(afA, bfr, accA, 0, 0, 0);
            accB = __builtin_amdgcn_mfma_f32_16x16x32_bf16(afB, bfr, accB, 0, 0, 0);
            if (tap == 13 && qk == 0) {   // V rides the center tap's A-frags
                s16x8 bv = *(const s16x8*)(wvlane + icb * 32);
                avA = __builtin_amdgcn_mfma_f32_16x16x32_bf16(afA, bv, avA, 0, 0, 0);
                avB = __builtin_amdgcn_mfma_f32_16x16x32_bf16(afB, bv, avB, 0, 0, 0);
            }
        }
    }

    // epilogue
    const float qs = 1.4426950408889634f / sgp[0];
    const int oc = oc0 + j, h = oc / HD, hd = oc % HD;
    const float bb_ = qk ? bias_k[oc] : bias_q[oc];
    short* base = (qk ? Kb : Qb) + ((size_t)(b * NHH + h) * NN) * 32 + hd;
    short* ObA = base + (size_t)((d0 + 0) * 16 + 4 * g) * 32;
    short* ObB = base + (size_t)((d0 + 1) * 16 + 4 * g) * 32;
#pragma unroll
    for (int r = 0; r < 4; ++r) {
        float vA = accA[r] + bb_, vB = accB[r] + bb_;
        if (!qk) { vA *= qs; vB *= qs; }
        ObA[r * 32] = f2bf(vA);
        ObB[r * 32] = f2bf(vB);
    }
    if (qk == 0) {
        short* Vb = Vtp + (size_t)(b * NHH + h) * (32 * NN) + (size_t)hd * NN;
#pragma unroll
        for (int r = 0; r < 4; ++r) {
            int nA = d0 * 16 + 4 * g + r;
            int nB = nA + 16;
            int pnA = (nA & ~63) | ((nA & 15) << 2) | ((nA >> 4) & 3);
            int pnB = (nB & ~63) | ((nB & 15) << 2) | ((nB >> 4) & 3);
            Vb[pnA] = f2bf(avA[r]);
            Vb[pnB] = f2bf(avB[r]);
        }
    }
    // zero k-pad hd 24..31 of Qb/Kb for this block's 32 tokens (once: z==0, oct==0)
    if (z == 0 && oct == 0) {
        short* arr = qk ? Kb : Qb;
        const int n = (d0 + ((l >> 4) & 1)) * 16 + (l & 15);
#pragma unroll
        for (int it = 0; it < 2; ++it) {
            int h2 = (l >> 5) + 2 * it;
            *(s16x8*)(arr + ((size_t)(b * NHH + h2) * NN + n) * 32 + 24) =
                (s16x8){0, 0, 0, 0, 0, 0, 0, 0};
        }
    }
}

// MFMA flash attention, K-split x2: block = 2 waves, each wave 1280 keys (20 tiles),
// DPP softmax reduce, defer-max, LDS combine at the end.
#define SOFTMAX_R(r, mr, lr) {                                                  \
    float vmx = fmaxf(fmaxf(sf0[r], sf1[r]), fmaxf(sf2[r], sf3[r]));            \
    vmx = rmax16(vmx);                                                          \
    if (vmx > mr) {                                                             \
        float sc = exp2f(mr - vmx);                                             \
        lr *= sc; of0[r] *= sc; of1[r] *= sc; mr = vmx;                         \
    }                                                                           \
    float p0 = exp2f(sf0[r] - mr), p1 = exp2f(sf1[r] - mr);                     \
    float p2 = exp2f(sf2[r] - mr), p3 = exp2f(sf3[r] - mr);                     \
    lr += (p0 + p1) + (p2 + p3);                                                \
    s16x4 pw = { f2bf(p0), f2bf(p1), f2bf(p2), f2bf(p3) };                      \
    *(s16x4*)&Pw[(4 * g + r) * 64 + ((4 * j) ^ (g << 3))] = pw;                 \
}

__global__ __launch_bounds__(128) void attn_kernel(
        const short* __restrict__ Qb, const short* __restrict__ Kb,
        const short* __restrict__ Vtp, float* __restrict__ att) {
    __shared__ short P_lds[2][16 * 64];
    __shared__ float comb[64 * 17];
    const int bh = blockIdx.x & 15;            // idx%16=bh -> idx%8 pins bh to an XCD
    const int q0 = (blockIdx.x >> 4) * 16;
    const int b = bh >> 2, h = bh & 3;
    const int tid = threadIdx.x, wvid = tid >> 6, l = tid & 63;
    const int j = l & 15, g = l >> 4;
    short* Pw = P_lds[wvid];

    const short* Qp = Qb + ((size_t)bh * NN + q0 + j) * 32 + 8 * g;
    s16x8 qf = *(const s16x8*)Qp;                      // A-frag: Q rows, scaled
    const short* Kbase = Kb + (size_t)bh * NN * 32;
    const short* Vbase = Vtp + (size_t)bh * 32 * NN;

    f32x4 of0 = {0.f, 0.f, 0.f, 0.f};                  // O cols d=0..15
    f32x4 of1 = {0.f, 0.f, 0.f, 0.f};                  // O cols d=16..23 (+pad)
    float m0 = -1e30f, m1 = -1e30f, m2 = -1e30f, m3 = -1e30f;
    float l0 = 0.f, l1 = 0.f, l2 = 0.f, l3 = 0.f;
    const f32x4 z = {0.f, 0.f, 0.f, 0.f};

    const int tbeg = wvid * (NN / 2);
    for (int t0 = tbeg; t0 < tbeg + NN / 2; t0 += 64) {
        const short* kp = Kbase + (size_t)(t0 + j) * 32 + 8 * g;
        s16x8 kf0 = *(const s16x8*)(kp);               // B-frags: 4 key-tiles
        s16x8 kf1 = *(const s16x8*)(kp + 512);
        s16x8 kf2 = *(const s16x8*)(kp + 1024);
        s16x8 kf3 = *(const s16x8*)(kp + 1536);
        f32x4 sf0 = __builtin_amdgcn_mfma_f32_16x16x32_bf16(qf, kf0, z, 0, 0, 0);
        f32x4 sf1 = __builtin_amdgcn_mfma_f32_16x16x32_bf16(qf, kf1, z, 0, 0, 0);
        f32x4 sf2 = __builtin_amdgcn_mfma_f32_16x16x32_bf16(qf, kf2, z, 0, 0, 0);
        f32x4 sf3 = __builtin_amdgcn_mfma_f32_16x16x32_bf16(qf, kf3, z, 0, 0, 0);

        SOFTMAX_R(0, m0, l0)
        SOFTMAX_R(1, m1, l1)
        SOFTMAX_R(2, m2, l2)
        SOFTMAX_R(3, m3, l3)

        asm volatile("s_waitcnt lgkmcnt(0)" ::: "memory");
        __builtin_amdgcn_sched_barrier(0);

        // PV: A = P (LDS, pos-space), B = V (global, pre-permuted pos-space)
        s16x8 pa0 = *(const s16x8*)&Pw[j * 64 + ((8 * g) ^ ((j >> 2) << 3))];
        s16x8 pa1 = *(const s16x8*)&Pw[j * 64 + ((32 + 8 * g) ^ ((j >> 2) << 3))];
        const short* vp = Vbase + (size_t)j * NN + t0 + 8 * g;
        s16x8 vf00 = *(const s16x8*)(vp);              // d 0..15,  pos 0..31
        s16x8 vf01 = *(const s16x8*)(vp + 32);         // d 0..15,  pos 32..63
        s16x8 vf10 = *(const s16x8*)(vp + 16 * NN);    // d 16..31, pos 0..31
        s16x8 vf11 = *(const s16x8*)(vp + 16 * NN + 32);
        of0 = __builtin_amdgcn_mfma_f32_16x16x32_bf16(pa0, vf00, of0, 0, 0, 0);
        of0 = __builtin_amdgcn_mfma_f32_16x16x32_bf16(pa1, vf01, of0, 0, 0, 0);
        of1 = __builtin_amdgcn_mfma_f32_16x16x32_bf16(pa0, vf10, of1, 0, 0, 0);
        of1 = __builtin_amdgcn_mfma_f32_16x16x32_bf16(pa1, vf11, of1, 0, 0, 0);
    }

    if (wvid == 1) {
        float* cp = comb + l * 17;
        cp[0] = m0; cp[1] = m1; cp[2] = m2; cp[3] = m3;
        cp[4] = l0; cp[5] = l1; cp[6] = l2; cp[7] = l3;
        cp[8]  = of0[0]; cp[9]  = of0[1]; cp[10] = of0[2]; cp[11] = of0[3];
        cp[12] = of1[0]; cp[13] = of1[1]; cp[14] = of1[2]; cp[15] = of1[3];
    }
    __syncthreads();
    if (wvid != 0) return;

    const float* cp = comb + l * 17;
#define COMBINE_R(r, mr, lr) {                                                  \
    float mb = cp[r], lb = cp[4 + r];                                           \
    float mm = fmaxf(mr, mb);                                                   \
    float sa = exp2f(mr - mm), sb = exp2f(mb - mm);                             \
    lr = lr * sa + lb * sb;                                                     \
    of0[r] = of0[r] * sa + cp[8 + r]  * sb;                                     \
    of1[r] = of1[r] * sa + cp[12 + r] * sb;                                     \
}
    COMBINE_R(0, m0, l0)
    COMBINE_R(1, m1, l1)
    COMBINE_R(2, m2, l2)
    COMBINE_R(3, m3, l3)

    l0 = rsum16(l0); l1 = rsum16(l1); l2 = rsum16(l2); l3 = rsum16(l3);
    const float rl0 = 1.f / l0, rl1 = 1.f / l1, rl2 = 1.f / l2, rl3 = 1.f / l3;

    float* ob = att + ((size_t)b * NN + q0 + 4 * g) * CC + h * HD;
    ob[0 * CC + j] = of0[0] * rl0;
    ob[1 * CC + j] = of0[1] * rl1;
    ob[2 * CC + j] = of0[2] * rl2;
    ob[3 * CC + j] = of0[3] * rl3;
    if (j < 8) {
        ob[0 * CC + 16 + j] = of1[0] * rl0;
        ob[1 * CC + 16 + j] = of1[1] * rl1;
        ob[2 * CC + 16 + j] = of1[2] * rl2;
        ob[3 * CC + 16 + j] = of1[3] * rl3;
    }
}

// out[t,c] = bo[c] + sum_cp att[t,cp] * wo[c,cp]
__global__ __launch_bounds__(256) void proj_kernel(
        const float* __restrict__ att, const float* __restrict__ wo,
        const float* __restrict__ bo, float* __restrict__ out) {
    __shared__ float wt[CC][CC + 1];   // wt[cp][c] = wo[c][cp], padded
    for (int i = threadIdx.x; i < CC * CC; i += 256) {
        int c = i / CC, cp = i % CC;
        wt[cp][c] = wo[i];
    }
    __syncthreads();
    int idx = blockIdx.x * 256 + threadIdx.x;
    int c = idx % CC;
    int t = idx / CC;
    const float* ar = att + (size_t)t * CC;
    float s = bo[c];
#pragma unroll 8
    for (int cp = 0; cp < CC; ++cp) s += ar[cp] * wt[cp][c];
    out[idx] = s;
}

extern "C" void kernel_launch(void* const* d_in, const int* in_sizes, int n_in,
                              void* d_out, int out_size, void* d_ws, size_t ws_size,
                              hipStream_t stream) {
    const float* x     = (const float*)d_in[0];
    const float* sg    = (const float*)d_in[1];
    const float* wq    = (const float*)d_in[2];
    const float* bnq_g = (const float*)d_in[3];
    const float* bnq_b = (const float*)d_in[4];
    const float* bnq_m = (const float*)d_in[5];
    const float* bnq_v = (const float*)d_in[6];
    const float* wk    = (const float*)d_in[7];
    const float* bnk_g = (const float*)d_in[8];
    const float* bnk_b = (const float*)d_in[9];
    const float* bnk_m = (const float*)d_in[10];
    const float* bnk_v = (const float*)d_in[11];
    const float* wv    = (const float*)d_in[12];
    const float* wo    = (const float*)d_in[13];
    const float* bo    = (const float*)d_in[14];

    float* ws = (float*)d_ws;
    short* wq_b   = (short*)(ws + WS_WQ);
    short* wk_b   = (short*)(ws + WS_WK);
    short* wv_b   = (short*)(ws + WS_WV);
    float* bias_q = ws + WS_BQ;
    float* bias_k = ws + WS_BK;
    float* attw   = ws + WS_ATT;
    short* Qb     = (short*)(ws + WS_QB);
    short* Kb     = (short*)(ws + WS_KB);
    short* Vtp    = (short*)(ws + WS_VT);

    prep_w<<<dim3(CC), dim3(128), 0, stream>>>(wq, bnq_g, bnq_b, bnq_m, bnq_v, wq_b, bias_q);
    prep_w<<<dim3(CC), dim3(128), 0, stream>>>(wk, bnk_g, bnk_b, bnk_m, bnk_v, wk_b, bias_k);
    prep_v<<<dim3(18), dim3(512), 0, stream>>>(wv, wv_b);

    qkv_conv<<<dim3(DEPTH / 2, BB, 2), dim3(384), 0, stream>>>(
        x, wq_b, wk_b, wv_b, bias_q, bias_k, sg, Qb, Kb, Vtp);

    attn_kernel<<<dim3(NN / 16 * 16), dim3(128), 0, stream>>>(Qb, Kb, Vtp, attw);

    proj_kernel<<<dim3((BB * NN * CC) / 256), dim3(256), 0, stream>>>(attw, wo, bo, (float*)d_out);
}

// Round 6
// 133.479 us; speedup vs baseline: 9.5000x; 1.0482x over previous
//
#include <hip/hip_runtime.h>
#include <hip/hip_bf16.h>

#define BB 4
#define DEPTH 160
#define CC 96
#define NN 2560          // DEPTH*16
#define NHH 4
#define HD 24
#define THETA 0.6f
#define BN_EPS 1e-5f

typedef __attribute__((ext_vector_type(4))) float f32x4;
typedef __attribute__((ext_vector_type(8))) short s16x8;
typedef __attribute__((ext_vector_type(4))) short s16x4;
typedef __attribute__((ext_vector_type(2))) unsigned u32x2;
typedef __attribute__((ext_vector_type(4))) unsigned u32x4;

#if __has_builtin(__builtin_amdgcn_exp2f)
#define EXP2(x) __builtin_amdgcn_exp2f(x)
#else
#define EXP2(x) exp2f(x)
#endif

// ---------------------------------------------------------------------------
// Workspace layout (float slots):
//   wq_b  : bf16 [tap][oc][ic] 27*96*96 shorts  -> 124416 slots
//   wk_b  : 124416
//   wv_b  : bf16 [oc][ic] 9216 shorts           -> 4608
//   bias_q: 96, bias_k: 96 (fp32)
//   att   : fp32 [b][n][96]                     -> 983040
//   Qb    : bf16 [bh][n][32] (hd 24..31 zeroed) -> 655360
//   Kb    : bf16 [bh][n][32]                    -> 655360
//   Vtp   : bf16 [bh][32][n] transposed, natural key order; rows 24..31 zeroed
// ---------------------------------------------------------------------------
#define WS_WQ   0
#define WS_WK   124416
#define WS_WV   248832
#define WS_BQ   253440
#define WS_BK   253536
#define WS_ATT  253632
#define WS_QB   1236672
#define WS_KB   1892032
#define WS_VT   2547392

__device__ __forceinline__ short f2bf(float f) {
    unsigned u = __float_as_uint(f);
    u += 0x7fffu + ((u >> 16) & 1u);
    return (short)(u >> 16);
}
__device__ __forceinline__ unsigned bf16pk(float lo, float hi) {
    unsigned r;
    asm("v_cvt_pk_bf16_f32 %0, %1, %2" : "=v"(r) : "v"(lo), "v"(hi));
    return r;
}

// Fold TCDC center-tap correction + BN scale into conv weights; bf16 [tap][oc][ic].
__global__ void prep_w(const float* __restrict__ w, const float* __restrict__ gamma,
                       const float* __restrict__ beta, const float* __restrict__ mean,
                       const float* __restrict__ var, short* __restrict__ w_eff,
                       float* __restrict__ bias) {
    int oc = blockIdx.x;
    int ic = threadIdx.x;
    if (ic >= CC) return;
    float scale = gamma[oc] * rsqrtf(var[oc] + BN_EPS);
    if (ic == 0) bias[oc] = beta[oc] - mean[oc] * scale;
    const float* wp = w + (oc * CC + ic) * 27;
    float kdiff = 0.f;
#pragma unroll
    for (int t = 0; t < 9; ++t) kdiff += wp[t] + wp[18 + t];
#pragma unroll
    for (int t = 0; t < 27; ++t) {
        float v = wp[t];
        if (t == 13) v -= THETA * kdiff;     // center tap (1,1,1)
        w_eff[t * (CC * CC) + oc * CC + ic] = f2bf(v * scale);
    }
}

__global__ void prep_v(const float* __restrict__ wv, short* __restrict__ wv_b) {
    int i = blockIdx.x * 512 + threadIdx.x;
    if (i < CC * CC) wv_b[i] = f2bf(wv[i]);
}

// MFMA im2col conv. Block = (2 depth slices) x (oc-half); 6 waves = qk(2) x oct(3).
__global__ __launch_bounds__(384, 4) void qkv_conv(
        const float* __restrict__ x, const short* __restrict__ wq_b,
        const short* __restrict__ wk_b, const short* __restrict__ wv_b,
        const float* __restrict__ bias_q, const float* __restrict__ bias_k,
        const float* __restrict__ sgp,
        short* __restrict__ Qb, short* __restrict__ Kb, short* __restrict__ Vtp) {
    __shared__ __align__(16) short xs[65 * 104];   // 64 rows + zero row, stride 104
    const int b = blockIdx.y;
    const int d0 = blockIdx.x * 2;
    const int z = blockIdx.z;                       // oc-half
    const int tid = threadIdx.x;

    // stage 4 slices (d0-1 .. d0+2), f32 -> bf16 via cvt_pk
#pragma unroll
    for (int k = 0; k < 4; ++k) {
        int c = tid + k * 384;                      // 1536 chunks
        int row = c / 24, ic0 = (c % 24) * 4;
        int dg = d0 - 1 + (row >> 4), pos = row & 15;
        u32x2 o = {0u, 0u};
        if (dg >= 0 && dg < DEPTH) {
            f32x4 v = *(const f32x4*)(x + ((size_t)(b * NN + dg * 16 + pos)) * CC + ic0);
            o[0] = bf16pk(v[0], v[1]);
            o[1] = bf16pk(v[2], v[3]);
        }
        *(u32x2*)&xs[row * 104 + ic0] = o;
    }
    if (tid < 26) *(u32x2*)&xs[64 * 104 + tid * 4] = (u32x2){0u, 0u};
    __syncthreads();

    const int w  = tid >> 6, l = tid & 63;
    const int qk = w / 3, oct = w % 3;
    const int j  = l & 15, g = l >> 4;
    const int oc0 = z * 48 + oct * 16;
    const int hj = j >> 2, wj = j & 3;

    const short* wlane  = (qk ? wk_b : wq_b) + (oc0 + j) * CC + 8 * g;
    const short* wvlane = wv_b + (oc0 + j) * CC + 8 * g;

    f32x4 accA = {0,0,0,0}, accB = {0,0,0,0};
    f32x4 avA  = {0,0,0,0}, avB  = {0,0,0,0};

#pragma unroll
    for (int kd = 0; kd < 3; ++kd)
#pragma unroll
    for (int kh = 0; kh < 3; ++kh)
#pragma unroll
    for (int kw = 0; kw < 3; ++kw) {
        const int tap = kd * 9 + kh * 3 + kw;
        const int hh = hj + kh - 1, ww = wj + kw - 1;
        const bool valid = ((unsigned)hh < 4u) && ((unsigned)ww < 4u);
        const int rA = valid ? (kd * 16 + hh * 4 + ww) : 64;       // slice t=0
        const int rB = valid ? ((1 + kd) * 16 + hh * 4 + ww) : 64; // slice t=1
        const short* xrA = &xs[rA * 104 + 8 * g];
        const short* xrB = &xs[rB * 104 + 8 * g];
        const short* wt = wlane + tap * (CC * CC);
#pragma unroll
        for (int icb = 0; icb < 3; ++icb) {
            s16x8 bfr = *(const s16x8*)(wt + icb * 32);
            s16x8 afA = *(const s16x8*)(xrA + icb * 32);
            s16x8 afB = *(const s16x8*)(xrB + icb * 32);
            accA = __builtin_amdgcn_mfma_f32_16x16x32_bf16(afA, bfr, accA, 0, 0, 0);
            accB = __builtin_amdgcn_mfma_f32_16x16x32_bf16(afB, bfr, accB, 0, 0, 0);
            if (tap == 13 && qk == 0) {   // V rides the center tap's A-frags
                s16x8 bv = *(const s16x8*)(wvlane + icb * 32);
                avA = __builtin_amdgcn_mfma_f32_16x16x32_bf16(afA, bv, avA, 0, 0, 0);
                avB = __builtin_amdgcn_mfma_f32_16x16x32_bf16(afB, bv, avB, 0, 0, 0);
            }
        }
    }

    // epilogue
    const float qs = 1.4426950408889634f / sgp[0];
    const int oc = oc0 + j, h = oc / HD, hd = oc % HD;
    const float bb_ = qk ? bias_k[oc] : bias_q[oc];
    short* base = (qk ? Kb : Qb) + ((size_t)(b * NHH + h) * NN) * 32 + hd;
    short* ObA = base + (size_t)((d0 + 0) * 16 + 4 * g) * 32;
    short* ObB = base + (size_t)((d0 + 1) * 16 + 4 * g) * 32;
#pragma unroll
    for (int r = 0; r < 4; ++r) {
        float vA = accA[r] + bb_, vB = accB[r] + bb_;
        if (!qk) { vA *= qs; vB *= qs; }
        ObA[r * 32] = f2bf(vA);
        ObB[r * 32] = f2bf(vB);
    }
    if (qk == 0) {
        short* Vb = Vtp + (size_t)(b * NHH + h) * (32 * NN) + (size_t)hd * NN;
#pragma unroll
        for (int r = 0; r < 4; ++r) {
            int nA = d0 * 16 + 4 * g + r;     // natural order (no permute)
            Vb[nA] = f2bf(avA[r]);
            Vb[nA + 16] = f2bf(avB[r]);
        }
    }
    // zero pads once per token-block (z==0, oct==0; both qk waves):
    //   Qb/Kb hd 24..31 (contracted in attn MFMA) and Vtp rows 24..31 (A-frag reads)
    if (z == 0 && oct == 0) {
        short* arr = qk ? Kb : Qb;
        const int n = (d0 + ((l >> 4) & 1)) * 16 + (l & 15);
#pragma unroll
        for (int it = 0; it < 2; ++it) {
            int h2 = (l >> 5) + 2 * it;
            *(s16x8*)(arr + ((size_t)(b * NHH + h2) * NN + n) * 32 + 24) =
                (s16x8){0, 0, 0, 0, 0, 0, 0, 0};
        }
        const int h3 = qk * 2 + (l >> 5);     // w0: heads 0,1; w3: heads 2,3
        short* Vb3 = Vtp + (size_t)(b * NHH + h3) * (32 * NN) + n;
#pragma unroll
        for (int hp = 24; hp < 32; ++hp)
            Vb3[(size_t)hp * NN] = 0;
    }
}

// MFMA flash attention, lane-local softmax (swapped operands):
//   QK^T = mfma(K, Q): lane (j,g) holds 16 scores, all for q-row j.
//   PV   = mfma(V^T, P): O^T accumulator also indexed by q-row j.
// K-split x2 across 2 waves; P exchange through LDS bracketed by __syncthreads
// (full compiler+HW fences; both waves run identical trip counts).
__global__ __launch_bounds__(128) void attn_kernel(
        const short* __restrict__ Qb, const short* __restrict__ Kb,
        const short* __restrict__ Vtp, float* __restrict__ att) {
    __shared__ __align__(16) unsigned P_lds[2][16 * 36];  // per wave [16 q][36 dw pad]
    __shared__ __align__(16) float comb[64 * 12];
    const int bh = blockIdx.x & 15;            // pins bh pairs per XCD for L2 reuse
    const int q0 = (blockIdx.x >> 4) * 16;
    const int b = bh >> 2, h = bh & 3;
    const int tid = threadIdx.x, wvid = tid >> 6, l = tid & 63;
    const int j = l & 15, g = l >> 4;
    unsigned* Pw = P_lds[wvid];

    const s16x8 qf = *(const s16x8*)(Qb + ((size_t)bh * NN + q0 + j) * 32 + 8 * g);
    const short* Kbase = Kb + (size_t)bh * NN * 32 + (size_t)j * 32 + 8 * g;
    const short* Vb0 = Vtp + (size_t)bh * 32 * NN + (size_t)j * NN + 8 * g;
    const short* Vb1 = Vb0 + 16 * NN;

    f32x4 oA = {0,0,0,0};                      // O[q j][dims 4g..4g+3]
    f32x4 oB = {0,0,0,0};                      // O[q j][dims 16+4g..] (g<2 real)
    float mx = -1e30f, lp = 0.f;
    const f32x4 z = {0,0,0,0};

    const int tbeg = wvid * (NN / 2);
    for (int t0 = tbeg; t0 < tbeg + NN / 2; t0 += 64) {
        const short* kp = Kbase + (size_t)t0 * 32;
        s16x8 k0 = *(const s16x8*)(kp);
        s16x8 k1 = *(const s16x8*)(kp + 512);
        s16x8 k2 = *(const s16x8*)(kp + 1024);
        s16x8 k3 = *(const s16x8*)(kp + 1536);
        f32x4 s0 = __builtin_amdgcn_mfma_f32_16x16x32_bf16(k0, qf, z, 0, 0, 0);
        f32x4 s1 = __builtin_amdgcn_mfma_f32_16x16x32_bf16(k1, qf, z, 0, 0, 0);
        f32x4 s2 = __builtin_amdgcn_mfma_f32_16x16x32_bf16(k2, qf, z, 0, 0, 0);
        f32x4 s3 = __builtin_amdgcn_mfma_f32_16x16x32_bf16(k3, qf, z, 0, 0, 0);

        // row max: in-register tree + 2 cross-g shuffles
        float v0 = fmaxf(fmaxf(s0[0], s0[1]), fmaxf(s0[2], s0[3]));
        float v1 = fmaxf(fmaxf(s1[0], s1[1]), fmaxf(s1[2], s1[3]));
        float v2 = fmaxf(fmaxf(s2[0], s2[1]), fmaxf(s2[2], s2[3]));
        float v3 = fmaxf(fmaxf(s3[0], s3[1]), fmaxf(s3[2], s3[3]));
        float vmx = fmaxf(fmaxf(v0, v1), fmaxf(v2, v3));
        vmx = fmaxf(vmx, __shfl_xor(vmx, 16));
        vmx = fmaxf(vmx, __shfl_xor(vmx, 32));

        float nm = fmaxf(mx, vmx);             // branchless online rescale
        float sc = EXP2(mx - nm);
        mx = nm;
        lp *= sc; oA *= sc; oB *= sc;

        float p00 = EXP2(s0[0] - mx), p01 = EXP2(s0[1] - mx);
        float p02 = EXP2(s0[2] - mx), p03 = EXP2(s0[3] - mx);
        float p10 = EXP2(s1[0] - mx), p11 = EXP2(s1[1] - mx);
        float p12 = EXP2(s1[2] - mx), p13 = EXP2(s1[3] - mx);
        float p20 = EXP2(s2[0] - mx), p21 = EXP2(s2[1] - mx);
        float p22 = EXP2(s2[2] - mx), p23 = EXP2(s2[3] - mx);
        float p30 = EXP2(s3[0] - mx), p31 = EXP2(s3[1] - mx);
        float p32 = EXP2(s3[2] - mx), p33 = EXP2(s3[3] - mx);
        lp += (((p00 + p01) + (p02 + p03)) + ((p10 + p11) + (p12 + p13)))
            + (((p20 + p21) + (p22 + p23)) + ((p30 + p31) + (p32 + p33)));

        // pack P: lane (j,g), m-th MFMA -> dword cols 8m+2g of row j
        unsigned* pr = Pw + j * 36 + 2 * g;
        *(u32x2*)(pr +  0) = (u32x2){bf16pk(p00, p01), bf16pk(p02, p03)};
        *(u32x2*)(pr +  8) = (u32x2){bf16pk(p10, p11), bf16pk(p12, p13)};
        *(u32x2*)(pr + 16) = (u32x2){bf16pk(p20, p21), bf16pk(p22, p23)};
        *(u32x2*)(pr + 24) = (u32x2){bf16pk(p30, p31), bf16pk(p32, p33)};

        __syncthreads();                       // full fence: writes visible, no reorder

        // PV: A = V^T (dims j rows), B = P (q j rows); both key-natural order
        u32x4 a0 = *(const u32x4*)&Pw[j * 36 + 4 * g];        // keys +0..31
        u32x4 a1 = *(const u32x4*)&Pw[j * 36 + 16 + 4 * g];   // keys +32..63
        s16x8 P0 = __builtin_bit_cast(s16x8, a0);
        s16x8 P1 = __builtin_bit_cast(s16x8, a1);
        s16x8 vA0 = *(const s16x8*)(Vb0 + t0);
        s16x8 vA1 = *(const s16x8*)(Vb0 + t0 + 32);
        s16x8 vB0 = *(const s16x8*)(Vb1 + t0);
        s16x8 vB1 = *(const s16x8*)(Vb1 + t0 + 32);
        oA = __builtin_amdgcn_mfma_f32_16x16x32_bf16(vA0, P0, oA, 0, 0, 0);
        oA = __builtin_amdgcn_mfma_f32_16x16x32_bf16(vA1, P1, oA, 0, 0, 0);
        oB = __builtin_amdgcn_mfma_f32_16x16x32_bf16(vB0, P0, oB, 0, 0, 0);
        oB = __builtin_amdgcn_mfma_f32_16x16x32_bf16(vB1, P1, oB, 0, 0, 0);

        __syncthreads();                       // reads drained before next writes
    }

    // row-sum across the 4 g-lanes
    lp += __shfl_xor(lp, 16);
    lp += __shfl_xor(lp, 32);

    if (wvid == 1) {
        float* cp = comb + l * 12;
        cp[0] = mx; cp[1] = lp;
        *(f32x4*)(cp + 4) = oA;
        *(f32x4*)(cp + 8) = oB;
    }
    __syncthreads();
    if (wvid != 0) return;

    const float* cp = comb + l * 12;
    float mb = cp[0], lb = cp[1];
    f32x4 oAb = *(const f32x4*)(cp + 4);
    f32x4 oBb = *(const f32x4*)(cp + 8);
    float mm = fmaxf(mx, mb);
    float sa = EXP2(mx - mm), sb = EXP2(mb - mm);
    float lt = lp * sa + lb * sb;
    float rl = 1.f / lt;
    sa *= rl; sb *= rl;
    f32x4 rA = oA * sa + oAb * sb;
    f32x4 rB = oB * sa + oBb * sb;

    float* op = att + ((size_t)b * NN + q0 + j) * CC + h * HD;
    *(f32x4*)(op + 4 * g) = rA;
    if (g < 2) *(f32x4*)(op + 16 + 4 * g) = rB;
}

// out[t,c] = bo[c] + sum_cp att[t,cp] * wo[c,cp]
__global__ __launch_bounds__(256) void proj_kernel(
        const float* __restrict__ att, const float* __restrict__ wo,
        const float* __restrict__ bo, float* __restrict__ out) {
    __shared__ float wt[CC][CC + 1];   // wt[cp][c] = wo[c][cp], padded
    for (int i = threadIdx.x; i < CC * CC; i += 256) {
        int c = i / CC, cp = i % CC;
        wt[cp][c] = wo[i];
    }
    __syncthreads();
    int idx = blockIdx.x * 256 + threadIdx.x;
    int c = idx % CC;
    int t = idx / CC;
    const float* ar = att + (size_t)t * CC;
    float s = bo[c];
#pragma unroll 8
    for (int cp = 0; cp < CC; ++cp) s += ar[cp] * wt[cp][c];
    out[idx] = s;
}

extern "C" void kernel_launch(void* const* d_in, const int* in_sizes, int n_in,
                              void* d_out, int out_size, void* d_ws, size_t ws_size,
                              hipStream_t stream) {
    const float* x     = (const float*)d_in[0];
    const float* sg    = (const float*)d_in[1];
    const float* wq    = (const float*)d_in[2];
    const float* bnq_g = (const float*)d_in[3];
    const float* bnq_b = (const float*)d_in[4];
    const float* bnq_m = (const float*)d_in[5];
    const float* bnq_v = (const float*)d_in[6];
    const float* wk    = (const float*)d_in[7];
    const float* bnk_g = (const float*)d_in[8];
    const float* bnk_b = (const float*)d_in[9];
    const float* bnk_m = (const float*)d_in[10];
    const float* bnk_v = (const float*)d_in[11];
    const float* wv    = (const float*)d_in[12];
    const float* wo    = (const float*)d_in[13];
    const float* bo    = (const float*)d_in[14];

    float* ws = (float*)d_ws;
    short* wq_b   = (short*)(ws + WS_WQ);
    short* wk_b   = (short*)(ws + WS_WK);
    short* wv_b   = (short*)(ws + WS_WV);
    float* bias_q = ws + WS_BQ;
    float* bias_k = ws + WS_BK;
    float* attw   = ws + WS_ATT;
    short* Qb     = (short*)(ws + WS_QB);
    short* Kb     = (short*)(ws + WS_KB);
    short* Vtp    = (short*)(ws + WS_VT);

    prep_w<<<dim3(CC), dim3(128), 0, stream>>>(wq, bnq_g, bnq_b, bnq_m, bnq_v, wq_b, bias_q);
    prep_w<<<dim3(CC), dim3(128), 0, stream>>>(wk, bnk_g, bnk_b, bnk_m, bnk_v, wk_b, bias_k);
    prep_v<<<dim3(18), dim3(512), 0, stream>>>(wv, wv_b);

    qkv_conv<<<dim3(DEPTH / 2, BB, 2), dim3(384), 0, stream>>>(
        x, wq_b, wk_b, wv_b, bias_q, bias_k, sg, Qb, Kb, Vtp);

    attn_kernel<<<dim3(NN / 16 * 16), dim3(128), 0, stream>>>(Qb, Kb, Vtp, attw);

    proj_kernel<<<dim3((BB * NN * CC) / 256), dim3(256), 0, stream>>>(attw, wo, bo, (float*)d_out);
}

// Round 7
// 133.264 us; speedup vs baseline: 9.5153x; 1.0016x over previous
//
#include <hip/hip_runtime.h>
#include <hip/hip_bf16.h>

#define BB 4
#define DEPTH 160
#define CC 96
#define NN 2560          // DEPTH*16
#define NHH 4
#define HD 24
#define THETA 0.6f
#define BN_EPS 1e-5f

typedef __attribute__((ext_vector_type(4))) float f32x4;
typedef __attribute__((ext_vector_type(8))) short s16x8;
typedef __attribute__((ext_vector_type(4))) short s16x4;
typedef __attribute__((ext_vector_type(2))) unsigned u32x2;
typedef __attribute__((ext_vector_type(4))) unsigned u32x4;

#if __has_builtin(__builtin_amdgcn_exp2f)
#define EXP2(x) __builtin_amdgcn_exp2f(x)
#else
#define EXP2(x) exp2f(x)
#endif

// ---------------------------------------------------------------------------
// Workspace layout (float slots):
//   wq_b  : bf16 [tap][oc][ic] 27*96*96 shorts  -> 124416 slots
//   wk_b  : 124416
//   wv_b  : bf16 [oc][ic] 9216 shorts           -> 4608
//   bias_q: 96, bias_k: 96 (fp32)
//   att   : fp32 [b][n][96]                     -> 983040
//   Qb    : bf16 [bh][n][32] (hd 24..31 zeroed) -> 655360
//   Kb    : bf16 [bh][n][32]                    -> 655360
//   Vtp   : bf16 [bh][32][n], vpos-permuted within 32-token halves; rows 24..31 zero
// ---------------------------------------------------------------------------
#define WS_WQ   0
#define WS_WK   124416
#define WS_WV   248832
#define WS_BQ   253440
#define WS_BK   253536
#define WS_ATT  253632
#define WS_QB   1236672
#define WS_KB   1892032
#define WS_VT   2547392

__device__ __forceinline__ short f2bf(float f) {
    unsigned u = __float_as_uint(f);
    u += 0x7fffu + ((u >> 16) & 1u);
    return (short)(u >> 16);
}
__device__ __forceinline__ unsigned bf16pk(float lo, float hi) {
    unsigned r;
    asm("v_cvt_pk_bf16_f32 %0, %1, %2" : "=v"(r) : "v"(lo), "v"(hi));
    return r;
}
// PV k-slot permutation: position where key n must be stored in Vtp so the
// P fragment is the lane's own QK^T output (in-register, no exchange).
__device__ __forceinline__ int vpos(int n) {
    return (n & ~31) | (((n >> 2) & 3) << 3) | (((n >> 4) & 1) << 2) | (n & 3);
}

// Fold TCDC center-tap correction + BN scale into conv weights; bf16 [tap][oc][ic].
__global__ void prep_w(const float* __restrict__ w, const float* __restrict__ gamma,
                       const float* __restrict__ beta, const float* __restrict__ mean,
                       const float* __restrict__ var, short* __restrict__ w_eff,
                       float* __restrict__ bias) {
    int oc = blockIdx.x;
    int ic = threadIdx.x;
    if (ic >= CC) return;
    float scale = gamma[oc] * rsqrtf(var[oc] + BN_EPS);
    if (ic == 0) bias[oc] = beta[oc] - mean[oc] * scale;
    const float* wp = w + (oc * CC + ic) * 27;
    float kdiff = 0.f;
#pragma unroll
    for (int t = 0; t < 9; ++t) kdiff += wp[t] + wp[18 + t];
#pragma unroll
    for (int t = 0; t < 27; ++t) {
        float v = wp[t];
        if (t == 13) v -= THETA * kdiff;     // center tap (1,1,1)
        w_eff[t * (CC * CC) + oc * CC + ic] = f2bf(v * scale);
    }
}

__global__ void prep_v(const float* __restrict__ wv, short* __restrict__ wv_b) {
    int i = blockIdx.x * 512 + threadIdx.x;
    if (i < CC * CC) wv_b[i] = f2bf(wv[i]);
}

// MFMA im2col conv. Block = (2 depth slices) x (oc-half); 6 waves = qk(2) x oct(3).
__global__ __launch_bounds__(384, 4) void qkv_conv(
        const float* __restrict__ x, const short* __restrict__ wq_b,
        const short* __restrict__ wk_b, const short* __restrict__ wv_b,
        const float* __restrict__ bias_q, const float* __restrict__ bias_k,
        const float* __restrict__ sgp,
        short* __restrict__ Qb, short* __restrict__ Kb, short* __restrict__ Vtp) {
    __shared__ __align__(16) short xs[65 * 104];   // 64 rows + zero row, stride 104
    const int b = blockIdx.y;
    const int d0 = blockIdx.x * 2;
    const int z = blockIdx.z;                       // oc-half
    const int tid = threadIdx.x;

    // stage 4 slices (d0-1 .. d0+2), f32 -> bf16 via cvt_pk
#pragma unroll
    for (int k = 0; k < 4; ++k) {
        int c = tid + k * 384;                      // 1536 chunks
        int row = c / 24, ic0 = (c % 24) * 4;
        int dg = d0 - 1 + (row >> 4), pos = row & 15;
        u32x2 o = {0u, 0u};
        if (dg >= 0 && dg < DEPTH) {
            f32x4 v = *(const f32x4*)(x + ((size_t)(b * NN + dg * 16 + pos)) * CC + ic0);
            o[0] = bf16pk(v[0], v[1]);
            o[1] = bf16pk(v[2], v[3]);
        }
        *(u32x2*)&xs[row * 104 + ic0] = o;
    }
    if (tid < 26) *(u32x2*)&xs[64 * 104 + tid * 4] = (u32x2){0u, 0u};
    __syncthreads();

    const int w  = tid >> 6, l = tid & 63;
    const int qk = w / 3, oct = w % 3;
    const int j  = l & 15, g = l >> 4;
    const int oc0 = z * 48 + oct * 16;
    const int hj = j >> 2, wj = j & 3;

    const short* wlane  = (qk ? wk_b : wq_b) + (oc0 + j) * CC + 8 * g;
    const short* wvlane = wv_b + (oc0 + j) * CC + 8 * g;

    f32x4 accA = {0,0,0,0}, accB = {0,0,0,0};
    f32x4 avA  = {0,0,0,0}, avB  = {0,0,0,0};

#pragma unroll
    for (int kd = 0; kd < 3; ++kd)
#pragma unroll
    for (int kh = 0; kh < 3; ++kh)
#pragma unroll
    for (int kw = 0; kw < 3; ++kw) {
        const int tap = kd * 9 + kh * 3 + kw;
        const int hh = hj + kh - 1, ww = wj + kw - 1;
        const bool valid = ((unsigned)hh < 4u) && ((unsigned)ww < 4u);
        const int rA = valid ? (kd * 16 + hh * 4 + ww) : 64;       // slice t=0
        const int rB = valid ? ((1 + kd) * 16 + hh * 4 + ww) : 64; // slice t=1
        const short* xrA = &xs[rA * 104 + 8 * g];
        const short* xrB = &xs[rB * 104 + 8 * g];
        const short* wt = wlane + tap * (CC * CC);
#pragma unroll
        for (int icb = 0; icb < 3; ++icb) {
            s16x8 bfr = *(const s16x8*)(wt + icb * 32);
            s16x8 afA = *(const s16x8*)(xrA + icb * 32);
            s16x8 afB = *(const s16x8*)(xrB + icb * 32);
            accA = __builtin_amdgcn_mfma_f32_16x16x32_bf16(afA, bfr, accA, 0, 0, 0);
            accB = __builtin_amdgcn_mfma_f32_16x16x32_bf16(afB, bfr, accB, 0, 0, 0);
            if (tap == 13 && qk == 0) {   // V rides the center tap's A-frags
                s16x8 bv = *(const s16x8*)(wvlane + icb * 32);
                avA = __builtin_amdgcn_mfma_f32_16x16x32_bf16(afA, bv, avA, 0, 0, 0);
                avB = __builtin_amdgcn_mfma_f32_16x16x32_bf16(afB, bv, avB, 0, 0, 0);
            }
        }
    }

    // epilogue
    const float qs = 1.4426950408889634f / sgp[0];
    const int oc = oc0 + j, h = oc / HD, hd = oc % HD;
    const float bb_ = qk ? bias_k[oc] : bias_q[oc];
    short* base = (qk ? Kb : Qb) + ((size_t)(b * NHH + h) * NN) * 32 + hd;
    short* ObA = base + (size_t)((d0 + 0) * 16 + 4 * g) * 32;
    short* ObB = base + (size_t)((d0 + 1) * 16 + 4 * g) * 32;
#pragma unroll
    for (int r = 0; r < 4; ++r) {
        float vA = accA[r] + bb_, vB = accB[r] + bb_;
        if (!qk) { vA *= qs; vB *= qs; }
        ObA[r * 32] = f2bf(vA);
        ObB[r * 32] = f2bf(vB);
    }
    if (qk == 0) {
        short* Vb = Vtp + (size_t)(b * NHH + h) * (32 * NN) + (size_t)hd * NN;
#pragma unroll
        for (int r = 0; r < 4; ++r) {
            int nA = d0 * 16 + 4 * g + r;
            Vb[vpos(nA)] = f2bf(avA[r]);
            Vb[vpos(nA + 16)] = f2bf(avB[r]);
        }
    }
    // zero pads once per token-block (z==0, oct==0; both qk waves):
    //   Qb/Kb hd 24..31 (contracted in attn MFMA) and Vtp rows 24..31 (A-frag reads)
    if (z == 0 && oct == 0) {
        short* arr = qk ? Kb : Qb;
        const int n = (d0 + ((l >> 4) & 1)) * 16 + (l & 15);
#pragma unroll
        for (int it = 0; it < 2; ++it) {
            int h2 = (l >> 5) + 2 * it;
            *(s16x8*)(arr + ((size_t)(b * NHH + h2) * NN + n) * 32 + 24) =
                (s16x8){0, 0, 0, 0, 0, 0, 0, 0};
        }
        const int h3 = qk * 2 + (l >> 5);     // qk=0: heads 0,1; qk=1: heads 2,3
        short* Vb3 = Vtp + (size_t)(b * NHH + h3) * (32 * NN) + n;
#pragma unroll
        for (int hp = 24; hp < 32; ++hp)
            Vb3[(size_t)hp * NN] = 0;         // whole row zero: permutation-safe
    }
}

// MFMA flash attention, fully in-register P (no LDS, no in-loop barriers):
//   QK^T = mfma(K, Q): lane (j,g) holds scores for q-row j, keys {16m+4g+r}.
//   PV k-slot (g,i) is DEFINED as key 16*(i>>2)+4g+(i&3), so the B-fragment is
//   the lane's own cvt_pk'd output; V is pre-stored with the matching vpos().
// K-split x2 across 2 waves; single LDS combine at the end.
__global__ __launch_bounds__(128) void attn_kernel(
        const short* __restrict__ Qb, const short* __restrict__ Kb,
        const short* __restrict__ Vtp, float* __restrict__ att) {
    __shared__ __align__(16) float comb[64 * 12];
    const int bh = blockIdx.x & 15;            // pins bh pairs per XCD for L2 reuse
    const int q0 = (blockIdx.x >> 4) * 16;
    const int b = bh >> 2, h = bh & 3;
    const int tid = threadIdx.x, wvid = tid >> 6, l = tid & 63;
    const int j = l & 15, g = l >> 4;

    const s16x8 qf = *(const s16x8*)(Qb + ((size_t)bh * NN + q0 + j) * 32 + 8 * g);
    const short* Kbase = Kb + (size_t)bh * NN * 32 + (size_t)j * 32 + 8 * g;
    const short* Vb0 = Vtp + (size_t)bh * 32 * NN + (size_t)j * NN + 8 * g;
    const short* Vb1 = Vb0 + 16 * NN;

    f32x4 oA = {0,0,0,0};                      // O[q j][dims 4g..4g+3]
    f32x4 oB = {0,0,0,0};                      // O[q j][dims 16+4g..] (g<2 real)
    float mx = -1e30f, lp = 0.f;
    const f32x4 z = {0,0,0,0};

    const int tbeg = wvid * (NN / 2);
    for (int t0 = tbeg; t0 < tbeg + NN / 2; t0 += 64) {
        const short* kp = Kbase + (size_t)t0 * 32;
        s16x8 k0 = *(const s16x8*)(kp);
        s16x8 k1 = *(const s16x8*)(kp + 512);
        s16x8 k2 = *(const s16x8*)(kp + 1024);
        s16x8 k3 = *(const s16x8*)(kp + 1536);
        f32x4 s0 = __builtin_amdgcn_mfma_f32_16x16x32_bf16(k0, qf, z, 0, 0, 0);
        f32x4 s1 = __builtin_amdgcn_mfma_f32_16x16x32_bf16(k1, qf, z, 0, 0, 0);
        f32x4 s2 = __builtin_amdgcn_mfma_f32_16x16x32_bf16(k2, qf, z, 0, 0, 0);
        f32x4 s3 = __builtin_amdgcn_mfma_f32_16x16x32_bf16(k3, qf, z, 0, 0, 0);

        // row max: in-register tree + 2 cross-g shuffles
        float v0 = fmaxf(fmaxf(s0[0], s0[1]), fmaxf(s0[2], s0[3]));
        float v1 = fmaxf(fmaxf(s1[0], s1[1]), fmaxf(s1[2], s1[3]));
        float v2 = fmaxf(fmaxf(s2[0], s2[1]), fmaxf(s2[2], s2[3]));
        float v3 = fmaxf(fmaxf(s3[0], s3[1]), fmaxf(s3[2], s3[3]));
        float vmx = fmaxf(fmaxf(v0, v1), fmaxf(v2, v3));
        vmx = fmaxf(vmx, __shfl_xor(vmx, 16));
        vmx = fmaxf(vmx, __shfl_xor(vmx, 32));

        float nm = fmaxf(mx, vmx);             // branchless online rescale
        float sc = EXP2(mx - nm);
        mx = nm;
        lp *= sc; oA *= sc; oB *= sc;

        float p00 = EXP2(s0[0] - mx), p01 = EXP2(s0[1] - mx);
        float p02 = EXP2(s0[2] - mx), p03 = EXP2(s0[3] - mx);
        float p10 = EXP2(s1[0] - mx), p11 = EXP2(s1[1] - mx);
        float p12 = EXP2(s1[2] - mx), p13 = EXP2(s1[3] - mx);
        float p20 = EXP2(s2[0] - mx), p21 = EXP2(s2[1] - mx);
        float p22 = EXP2(s2[2] - mx), p23 = EXP2(s2[3] - mx);
        float p30 = EXP2(s3[0] - mx), p31 = EXP2(s3[1] - mx);
        float p32 = EXP2(s3[2] - mx), p33 = EXP2(s3[3] - mx);
        lp += (((p00 + p01) + (p02 + p03)) + ((p10 + p11) + (p12 + p13)))
            + (((p20 + p21) + (p22 + p23)) + ((p30 + p31) + (p32 + p33)));

        // B-fragments: the lane's own values, in-register (k-slot map = vpos)
        u32x4 w0 = { bf16pk(p00, p01), bf16pk(p02, p03),
                     bf16pk(p10, p11), bf16pk(p12, p13) };   // keys 0..31
        u32x4 w1 = { bf16pk(p20, p21), bf16pk(p22, p23),
                     bf16pk(p30, p31), bf16pk(p32, p33) };   // keys 32..63
        s16x8 P0 = __builtin_bit_cast(s16x8, w0);
        s16x8 P1 = __builtin_bit_cast(s16x8, w1);

        s16x8 vA0 = *(const s16x8*)(Vb0 + t0);
        s16x8 vA1 = *(const s16x8*)(Vb0 + t0 + 32);
        s16x8 vB0 = *(const s16x8*)(Vb1 + t0);
        s16x8 vB1 = *(const s16x8*)(Vb1 + t0 + 32);
        oA = __builtin_amdgcn_mfma_f32_16x16x32_bf16(vA0, P0, oA, 0, 0, 0);
        oA = __builtin_amdgcn_mfma_f32_16x16x32_bf16(vA1, P1, oA, 0, 0, 0);
        oB = __builtin_amdgcn_mfma_f32_16x16x32_bf16(vB0, P0, oB, 0, 0, 0);
        oB = __builtin_amdgcn_mfma_f32_16x16x32_bf16(vB1, P1, oB, 0, 0, 0);
    }

    // row-sum across the 4 g-lanes
    lp += __shfl_xor(lp, 16);
    lp += __shfl_xor(lp, 32);

    if (wvid == 1) {
        float* cp = comb + l * 12;
        cp[0] = mx; cp[1] = lp;
        *(f32x4*)(cp + 4) = oA;
        *(f32x4*)(cp + 8) = oB;
    }
    __syncthreads();
    if (wvid != 0) return;

    const float* cp = comb + l * 12;
    float mb = cp[0], lb = cp[1];
    f32x4 oAb = *(const f32x4*)(cp + 4);
    f32x4 oBb = *(const f32x4*)(cp + 8);
    float mm = fmaxf(mx, mb);
    float sa = EXP2(mx - mm), sb = EXP2(mb - mm);
    float lt = lp * sa + lb * sb;
    float rl = 1.f / lt;
    sa *= rl; sb *= rl;
    f32x4 rA = oA * sa + oAb * sb;
    f32x4 rB = oB * sa + oBb * sb;

    float* op = att + ((size_t)b * NN + q0 + j) * CC + h * HD;
    *(f32x4*)(op + 4 * g) = rA;
    if (g < 2) *(f32x4*)(op + 16 + 4 * g) = rB;
}

// out[t,c] = bo[c] + sum_cp att[t,cp] * wo[c,cp]
__global__ __launch_bounds__(256) void proj_kernel(
        const float* __restrict__ att, const float* __restrict__ wo,
        const float* __restrict__ bo, float* __restrict__ out) {
    __shared__ float wt[CC][CC + 1];   // wt[cp][c] = wo[c][cp], padded
    for (int i = threadIdx.x; i < CC * CC; i += 256) {
        int c = i / CC, cp = i % CC;
        wt[cp][c] = wo[i];
    }
    __syncthreads();
    int idx = blockIdx.x * 256 + threadIdx.x;
    int c = idx % CC;
    int t = idx / CC;
    const float* ar = att + (size_t)t * CC;
    float s = bo[c];
#pragma unroll 8
    for (int cp = 0; cp < CC; ++cp) s += ar[cp] * wt[cp][c];
    out[idx] = s;
}

extern "C" void kernel_launch(void* const* d_in, const int* in_sizes, int n_in,
                              void* d_out, int out_size, void* d_ws, size_t ws_size,
                              hipStream_t stream) {
    const float* x     = (const float*)d_in[0];
    const float* sg    = (const float*)d_in[1];
    const float* wq    = (const float*)d_in[2];
    const float* bnq_g = (const float*)d_in[3];
    const float* bnq_b = (const float*)d_in[4];
    const float* bnq_m = (const float*)d_in[5];
    const float* bnq_v = (const float*)d_in[6];
    const float* wk    = (const float*)d_in[7];
    const float* bnk_g = (const float*)d_in[8];
    const float* bnk_b = (const float*)d_in[9];
    const float* bnk_m = (const float*)d_in[10];
    const float* bnk_v = (const float*)d_in[11];
    const float* wv    = (const float*)d_in[12];
    const float* wo    = (const float*)d_in[13];
    const float* bo    = (const float*)d_in[14];

    float* ws = (float*)d_ws;
    short* wq_b   = (short*)(ws + WS_WQ);
    short* wk_b   = (short*)(ws + WS_WK);
    short* wv_b   = (short*)(ws + WS_WV);
    float* bias_q = ws + WS_BQ;
    float* bias_k = ws + WS_BK;
    float* attw   = ws + WS_ATT;
    short* Qb     = (short*)(ws + WS_QB);
    short* Kb     = (short*)(ws + WS_KB);
    short* Vtp    = (short*)(ws + WS_VT);

    prep_w<<<dim3(CC), dim3(128), 0, stream>>>(wq, bnq_g, bnq_b, bnq_m, bnq_v, wq_b, bias_q);
    prep_w<<<dim3(CC), dim3(128), 0, stream>>>(wk, bnk_g, bnk_b, bnk_m, bnk_v, wk_b, bias_k);
    prep_v<<<dim3(18), dim3(512), 0, stream>>>(wv, wv_b);

    qkv_conv<<<dim3(DEPTH / 2, BB, 2), dim3(384), 0, stream>>>(
        x, wq_b, wk_b, wv_b, bias_q, bias_k, sg, Qb, Kb, Vtp);

    attn_kernel<<<dim3(NN / 16 * 16), dim3(128), 0, stream>>>(Qb, Kb, Vtp, attw);

    proj_kernel<<<dim3((BB * NN * CC) / 256), dim3(256), 0, stream>>>(attw, wo, bo, (float*)d_out);
}